// Round 13
// baseline (603.122 us; speedup 1.0000x reference)
//
#include <hip/hip_runtime.h>
#include <math.h>

typedef _Float16 f16;
typedef __attribute__((ext_vector_type(8))) _Float16 f16x8;
typedef __attribute__((ext_vector_type(4))) float f32x4;
typedef __attribute__((ext_vector_type(16))) float f32x16;

#define LPOS 4096      // 64*64 positions / patches
#define KPAT 576       // 64ch * 3*3 patch
#define KPATP 640      // Ph row stride, padded (cols 576..639 zeroed)
#define RPAT 2048      // 128ch * 4*4 raw patch
#define PPAD 20736     // 144*144 padded positions for ybT
#define ROWS 18432     // elems per padded row: 16 chunks * 144 x * 8

#define GLDS(g, l) __builtin_amdgcn_global_load_lds( \
    (const __attribute__((address_space(1))) void*)(g), \
    (__attribute__((address_space(3))) void*)(l), 16, 0, 0)

// ---------------------------------------------------------------------------
// Batched: Ph4[b][pos][640] = fp16 3x3x64 patches of x2[b] (zero pad 1),
// cols 576..639 zeroed; rnorm4[b][pos]
__global__ __launch_bounds__(64) void build_P_norm(const float* __restrict__ x2,
                                                   f16* __restrict__ Ph4,
                                                   float* __restrict__ rnorm4) {
    int bid = blockIdx.x;
    int b = bid >> 12, pos = bid & 4095;
    const float* x2b = x2 + (size_t)b * 64 * 4096;
    f16* Ph = Ph4 + (size_t)b * 4096 * KPATP;
    float* rnorm = rnorm4 + b * 4096;
    int u = pos >> 6, v = pos & 63;
    int tid = threadIdx.x;
    float ss = 0.f;
    for (int k = tid; k < KPAT; k += 64) {
        int c = k / 9, r9 = k % 9;
        int di = r9 / 3, dj = r9 % 3;
        int yy = u + di - 1, xx = v + dj - 1;
        float val = 0.f;
        if (yy >= 0 && yy < 64 && xx >= 0 && xx < 64)
            val = x2b[c * 4096 + yy * 64 + xx];
        Ph[pos * KPATP + k] = (f16)val;
        ss += val * val;
    }
    Ph[pos * KPATP + KPAT + tid] = (f16)0.f;   // zero the 64-wide K-pad tail
#pragma unroll
    for (int off = 32; off; off >>= 1) ss += __shfl_xor(ss, off, 64);
    if (tid == 0) rnorm[pos] = 1.f / fmaxf(sqrtf(ss), 1e-4f);
}

// ---------------------------------------------------------------------------
// All 4 batches in one launch: block b compacts mask[b] -> cidx[b], nk[b]
// nk[0] = nkeep, nk[1] = nkeep padded to 128 (deconv needs even 64-tiles)
__global__ __launch_bounds__(256) void compact_mask_all(const float* __restrict__ mask,
                                                        int* __restrict__ cidx_all,
                                                        int* __restrict__ nk_all) {
    int b = blockIdx.x;
    const float* maskb = mask + (size_t)b * 16384;
    int* cidx = cidx_all + b * 4352;
    int* nk = nk_all + b * 2;
    int tid = threadIdx.x;
    int keep[16];
    int cnt = 0;
#pragma unroll
    for (int e = 0; e < 16; ++e) {
        int pos = tid * 16 + e;
        int pu = pos >> 6, pv = pos & 63;
        float s = 0.f;
        for (int t = 0; t < 4; ++t)
            for (int w = 0; w < 4; ++w) {
                int yy = 2 * pu - 1 + t, xx = 2 * pv - 1 + w;
                if (yy >= 0 && yy < 128 && xx >= 0 && xx < 128)
                    s += maskb[yy * 128 + xx];
            }
        keep[e] = (s == 0.f) ? 1 : 0;
        cnt += keep[e];
    }
    __shared__ int ps[256];
    ps[tid] = cnt;
    __syncthreads();
    for (int off = 1; off < 256; off <<= 1) {
        int v = (tid >= off) ? ps[tid - off] : 0;
        __syncthreads();
        ps[tid] += v;
        __syncthreads();
    }
    int total = ps[255];
    int base = ps[tid] - cnt;   // exclusive prefix
#pragma unroll
    for (int e = 0; e < 16; ++e)
        if (keep[e]) cidx[base++] = tid * 16 + e;
    for (int i = total + tid; i < 4352; i += 256) cidx[i] = 0;
    if (tid == 0) { nk[0] = total; nk[1] = (total + 127) & ~127; }
}

// ---------------------------------------------------------------------------
// Zero the 8-wide halo of the padded chunk-major ybT buffer (all 4 batches)
__global__ __launch_bounds__(256) void zero_halo(f16* __restrict__ ybTp) {
    int idx = blockIdx.x * 256 + threadIdx.x;
    int b = idx / 331776; if (b >= 4) return;
    int rem = idx % 331776;                     // 144*144*16
    int q = rem & 15, pos = rem >> 4;
    int yy = pos / 144, xx = pos % 144;
    if (yy >= 8 && yy < 136 && xx >= 8 && xx < 136) return;
    *(f16x8*)(ybTp + (size_t)b * PPAD * 128 + (size_t)yy * ROWS + q * 1152 + xx * 8) = (f16x8){};
}

// ---------------------------------------------------------------------------
// S[m][j] (fp16) = Ph[m] . Ph[cidx[j]] * rnorm[cidx[j]]   (R10-PROVEN form,
// Ph row stride KPATP; K loop over the 576 real cols)
// 32x32x16 fp16 MFMA, BK=32, LDS XOR-swizzle slot = chunk ^ ((row>>1)&3).
__global__ __launch_bounds__(256) void gemm_score_mfma(const f16* __restrict__ Ph,
                                                       const int* __restrict__ cidx,
                                                       const float* __restrict__ rnorm,
                                                       const int* __restrict__ nk,
                                                       f16* __restrict__ S) {
    int n0 = blockIdx.x * 128;
    if (n0 >= nk[0]) return;    // fully-masked column tile
    __shared__ f16 Ash[128 * 32], Bsh[128 * 32];
    int tid = threadIdx.x;
    int w = tid >> 6, lane = tid & 63;
    int wy = w >> 1, wx = w & 1;
    int m0 = blockIdx.y * 128;
    f32x16 acc[2][2];
#pragma unroll
    for (int mt = 0; mt < 2; ++mt)
#pragma unroll
        for (int nt = 0; nt < 2; ++nt)
#pragma unroll
            for (int e = 0; e < 16; ++e) acc[mt][nt][e] = 0.f;
    int srow = lane >> 2;                          // 0..15 staging row
    int cblk = lane & 3;                           // LDS 16B chunk slot
    int scol = (cblk ^ ((srow >> 1) & 3)) * 8;     // swizzled global col
    int dcol = cblk * 8;
    int l31 = lane & 31, kh2 = lane >> 5;
    int arow[2], brow[2], asw[2], bsw[2];
#pragma unroll
    for (int i = 0; i < 2; ++i) {
        arow[i] = wy * 64 + i * 32 + l31;
        brow[i] = wx * 64 + i * 32 + l31;
        asw[i] = (arow[i] >> 1) & 3;
        bsw[i] = (brow[i] >> 1) & 3;
    }
    const f16* Asrc[2]; const f16* Bsrc[2]; int ldso[2];
#pragma unroll
    for (int i = 0; i < 2; ++i) {
        int row = w * 32 + i * 16 + srow;
        ldso[i] = row * 32 + dcol;
        Asrc[i] = Ph + (size_t)(m0 + row) * KPATP + scol;
        Bsrc[i] = Ph + (size_t)cidx[n0 + row] * KPATP + scol;
    }
    for (int k0 = 0; k0 < KPAT; k0 += 32) {
#pragma unroll
        for (int i = 0; i < 2; ++i) {
            GLDS(Asrc[i] + k0, Ash + ldso[i]);
            GLDS(Bsrc[i] + k0, Bsh + ldso[i]);
        }
        __syncthreads();
#pragma unroll
        for (int kh = 0; kh < 2; ++kh) {
            int blk = kh * 2 + kh2;                // logical 16B chunk in row
            f16x8 va[2], vb[2];
#pragma unroll
            for (int i = 0; i < 2; ++i) {
                va[i] = *(const f16x8*)&Ash[arow[i] * 32 + ((blk ^ asw[i]) * 8)];
                vb[i] = *(const f16x8*)&Bsh[brow[i] * 32 + ((blk ^ bsw[i]) * 8)];
            }
#pragma unroll
            for (int mt = 0; mt < 2; ++mt)
#pragma unroll
                for (int nt = 0; nt < 2; ++nt)
                    acc[mt][nt] = __builtin_amdgcn_mfma_f32_32x32x16_f16(va[mt], vb[nt], acc[mt][nt], 0, 0, 0);
        }
        __syncthreads();
    }
    int rbase = 4 * kh2;
#pragma unroll
    for (int mt = 0; mt < 2; ++mt)
#pragma unroll
        for (int nt = 0; nt < 2; ++nt) {
            int col = n0 + wx * 64 + nt * 32 + l31;
            float rn = rnorm[cidx[col]];
#pragma unroll
            for (int rg = 0; rg < 16; ++rg) {
                int row = m0 + wy * 64 + mt * 32 + (rg & 3) + 8 * (rg >> 2) + rbase;
                S[(size_t)row * LPOS + col] = (f16)(acc[mt][nt][rg] * rn);
            }
        }
}

// ---------------------------------------------------------------------------
// Masked softmax over compacted columns (f16x8 reads/writes).
// R12: skip S reads for whole 8-groups beyond kpad (always-masked anyway;
// kpad >= nkeep so partial groups keep the per-element mask). Same math.
__global__ __launch_bounds__(256) void softmax_mask(const f16* __restrict__ S,
                                                    const int* __restrict__ nk,
                                                    const float* __restrict__ mab,
                                                    f16* __restrict__ Ah) {
    int pos = blockIdx.x;
    int tid = threadIdx.x;
    int nkeep = nk[0], kpad = nk[1];
    float ma = mab[pos];
    float sc = 10.0f * ma;
    const f16* Srow = S + (size_t)pos * LPOS;
    float v[16];
    float vmax = (nkeep < LPOS) ? 0.f : -3.0e38f;
#pragma unroll
    for (int i = 0; i < 2; ++i) {
        int jb = (tid + i * 256) * 8;
        if (jb < kpad) {
            f16x8 x8 = *(const f16x8*)(Srow + jb);
#pragma unroll
            for (int e = 0; e < 8; ++e) {
                float x = (jb + e < nkeep) ? (float)x8[e] * sc : -3.0e38f;
                v[i * 8 + e] = x;
                vmax = fmaxf(vmax, x);
            }
        } else {
#pragma unroll
            for (int e = 0; e < 8; ++e) v[i * 8 + e] = -3.0e38f;
        }
    }
#pragma unroll
    for (int off = 32; off; off >>= 1) vmax = fmaxf(vmax, __shfl_xor(vmax, off, 64));
    __shared__ float sred[4];
    int wid = tid >> 6;
    if ((tid & 63) == 0) sred[wid] = vmax;
    __syncthreads();
    vmax = fmaxf(fmaxf(sred[0], sred[1]), fmaxf(sred[2], sred[3]));
    __syncthreads();
    float ssum = 0.f;
#pragma unroll
    for (int i = 0; i < 16; ++i) {
        float e = (v[i] > -1.0e37f) ? __expf(v[i] - vmax) : 0.f;
        v[i] = e;
        ssum += e;
    }
#pragma unroll
    for (int off = 32; off; off >>= 1) ssum += __shfl_xor(ssum, off, 64);
    if ((tid & 63) == 0) sred[wid] = ssum;
    __syncthreads();
    float total = sred[0] + sred[1] + sred[2] + sred[3]
                + (float)(LPOS - nkeep) * __expf(-vmax);
    float inv = 1.f / total;
#pragma unroll
    for (int i = 0; i < 2; ++i) {
        int jb = (tid + i * 256) * 8;
        if (jb >= kpad) continue;
        f16x8 h;
#pragma unroll
        for (int e = 0; e < 8; ++e)
            h[e] = (jb + e < nkeep) ? (f16)(v[i * 8 + e] * inv * ma) : (f16)0.f;
        *(f16x8*)(Ah + (size_t)pos * LPOS + jb) = h;
    }
}

// ---------------------------------------------------------------------------
// Rt[n][j] fp16, n = (t*4+s)*128 + c, patch p = cidx[j] (compacted gather)
__global__ __launch_bounds__(256) void build_Rt(const float* __restrict__ x1b,
                                                const int* __restrict__ cidx,
                                                const int* __restrict__ nk,
                                                f16* __restrict__ Rt) {
    int idx = blockIdx.x * 256 + threadIdx.x;   // n*4096 + j
    int j = idx & 4095, n = idx >> 12;
    if (j >= nk[1]) return;
    int p = cidx[j];
    int pu = p >> 6, pv = p & 63;
    int t = (n >> 9) & 3, s = (n >> 7) & 3, c = n & 127;
    int yy = 2 * pu - 1 + t, xx = 2 * pv - 1 + s;
    float val = 0.f;
    if (yy >= 0 && yy < 128 && xx >= 0 && xx < 128)
        val = x1b[c * 16384 + yy * 128 + xx];
    Rt[idx] = (f16)val;
}

// ---------------------------------------------------------------------------
// 128x128 8-PHASE DECONV, 2 blocks/CU (proven R7): V = Ah . Rt^T, fp16 out.
__global__ __launch_bounds__(256, 2) void gemm_deconv128(const f16* __restrict__ A,
                                                         const f16* __restrict__ Bt,
                                                         const int* __restrict__ nk,
                                                         f16* __restrict__ V) {
    __shared__ __align__(16) f16 L[32768];     // 65536 B
    int id = blockIdx.x;
    int orig = (id & 7) * 64 + (id >> 3);      // XCD-contiguous chunks
    int mt = orig >> 4, nt = orig & 15;
    int m0 = mt * 128, n0 = nt * 128;
    int kpad = nk[1];
    int ntile = kpad >> 6;                     // even (128-padded)
    int NI = ntile >> 1;

    int tid = threadIdx.x;
    int lane = tid & 63, wid = tid >> 6;
    int wy = wid >> 1, wx = wid & 1;           // 2M x 2N wave grid
    int r16 = lane & 15, q = lane >> 4;

    int sr = tid >> 3, sc = tid & 7;
    int colo = (sc ^ (sr & 7)) * 8;            // pre-swizzled global chunk
    const f16* pA = A  + (size_t)(m0 + sr) * 4096 + colo;
    const f16* pB = Bt + (size_t)(n0 + sr) * 4096 + colo;

    int s3 = r16 & 7;
    int qs = (q ^ (s3 & 3)) * 8;
    int kf = s3 >> 2;
    const f16* aB = L + (wy * 64 + r16) * 64 + qs;
    const f16* bB = L + 8192 + (wx * 64 + r16) * 64 + qs;

    f32x4 acc[4][4];
#pragma unroll
    for (int i = 0; i < 4; ++i)
#pragma unroll
        for (int j = 0; j < 4; ++j) acc[i][j] = (f32x4){0.f, 0.f, 0.f, 0.f};

    f16x8 af[2][2], b0[2][2], bc[2][2];

#define STGA(bf, u, kt) do { \
    int kk_ = ((kt) < ntile) ? (kt) * 64 : 0; \
    GLDS(pA + (size_t)(u) * 131072 + kk_, L + (bf) * 16384 + (u) * 2048 + tid * 8); \
} while (0)
#define STGB(bf, u, kt) do { \
    int kk_ = ((kt) < ntile) ? (kt) * 64 : 0; \
    GLDS(pB + (size_t)(u) * 131072 + kk_, L + (bf) * 16384 + 8192 + (u) * 2048 + tid * 8); \
} while (0)
#define RDA(bf, msub) do { \
    _Pragma("unroll") for (int mf_ = 0; mf_ < 2; ++mf_) \
    _Pragma("unroll") for (int ks_ = 0; ks_ < 2; ++ks_) \
        af[mf_][ks_] = *(const f16x8*)(aB + (bf) * 16384 + (msub) * 2048 + mf_ * 1024 + ((ks_ ^ kf) << 5)); \
} while (0)
#define RDB(dst, bf, nsub) do { \
    _Pragma("unroll") for (int nf_ = 0; nf_ < 2; ++nf_) \
    _Pragma("unroll") for (int ks_ = 0; ks_ < 2; ++ks_) \
        dst[nf_][ks_] = *(const f16x8*)(bB + (bf) * 16384 + (nsub) * 2048 + nf_ * 1024 + ((ks_ ^ kf) << 5)); \
} while (0)
#define QMM(msub, nsub, bfr) do { \
    __builtin_amdgcn_s_setprio(1); \
    _Pragma("unroll") for (int mf_ = 0; mf_ < 2; ++mf_) \
    _Pragma("unroll") for (int nf_ = 0; nf_ < 2; ++nf_) \
    _Pragma("unroll") for (int ks_ = 0; ks_ < 2; ++ks_) \
        acc[(msub) * 2 + mf_][(nsub) * 2 + nf_] = __builtin_amdgcn_mfma_f32_16x16x32_f16( \
            af[mf_][ks_], bfr[nf_][ks_], acc[(msub) * 2 + mf_][(nsub) * 2 + nf_], 0, 0, 0); \
    __builtin_amdgcn_s_setprio(0); \
} while (0)
#define BAR()  __builtin_amdgcn_s_barrier()
#define VMW4() asm volatile("s_waitcnt vmcnt(4)" ::: "memory")

    STGB(0, 0, 0); STGB(0, 1, 0); STGB(0, 2, 0); STGB(0, 3, 0);
    STGA(0, 0, 0); STGA(0, 1, 0); STGA(0, 2, 0); STGA(0, 3, 0);
    STGB(1, 0, 1); STGB(1, 1, 1); STGB(1, 2, 1); STGB(1, 3, 1);
    VMW4(); BAR();

    for (int i = 0; i < NI; ++i) {
        int kt1 = 2 * i + 1, kt2 = 2 * i + 2, kt3 = 2 * i + 3;
        RDA(0, 0); RDB(b0, 0, 0);
        STGA(1, 0, kt1); STGA(1, 1, kt1);
        BAR(); QMM(0, 0, b0); BAR();
        RDB(bc, 0, 1);
        STGA(1, 2, kt1); STGA(1, 3, kt1);
        BAR(); QMM(0, 1, bc); BAR();
        RDA(0, 1);
        STGB(0, 0, kt2); STGB(0, 1, kt2);
        BAR(); QMM(1, 1, bc); BAR();
        STGB(0, 2, kt2); STGB(0, 3, kt2);
        BAR(); QMM(1, 0, b0);
        VMW4(); BAR();
        RDA(1, 0); RDB(b0, 1, 0);
        STGA(0, 0, kt2); STGA(0, 1, kt2);
        BAR(); QMM(0, 0, b0); BAR();
        RDB(bc, 1, 1);
        STGA(0, 2, kt2); STGA(0, 3, kt2);
        BAR(); QMM(0, 1, bc); BAR();
        RDA(1, 1);
        STGB(1, 0, kt3); STGB(1, 1, kt3);
        BAR(); QMM(1, 1, bc); BAR();
        STGB(1, 2, kt3); STGB(1, 3, kt3);
        BAR(); QMM(1, 0, b0);
        VMW4(); BAR();
    }

    asm volatile("s_waitcnt vmcnt(0)" ::: "memory");

#pragma unroll
    for (int mi = 0; mi < 4; ++mi) {
        int row = m0 + wy * 64 + mi * 16 + q * 4;
#pragma unroll
        for (int ni = 0; ni < 4; ++ni) {
            int col = n0 + wx * 64 + ni * 16 + r16;
#pragma unroll
            for (int g = 0; g < 4; ++g)
                V[(size_t)(row + g) * RPAT + col] = (f16)acc[mi][ni][g];
        }
    }
#undef STGA
#undef STGB
#undef RDA
#undef RDB
#undef QMM
#undef BAR
#undef VMW4
}

// ---------------------------------------------------------------------------
// reconstruct -> chunk-major padded layout:
// ybTp[b][yy+8][q=c>>3][xx+8][c&7] = 0.25 * sum over valid taps of V
__global__ __launch_bounds__(256) void reconstruct(const f16* __restrict__ V,
                                                   f16* __restrict__ ybTpb) {
    int idx = blockIdx.x * 256 + threadIdx.x;   // p*128 + c
    int c = idx & 127, p = idx >> 7;
    int xx = p & 127, yy = p >> 7;
    float sum = 0.f;
    int tby = (yy & 1) ? 0 : 1;
    int tbx = (xx & 1) ? 0 : 1;
#pragma unroll
    for (int dt = 0; dt < 2; ++dt) {
        int t = tby + 2 * dt;
        int u2 = yy + 1 - t;
        if (u2 < 0 || u2 >= 128) continue;
        int u = u2 >> 1;
#pragma unroll
        for (int ds = 0; ds < 2; ++ds) {
            int s = tbx + 2 * ds;
            int v2 = xx + 1 - s;
            if (v2 < 0 || v2 >= 128) continue;
            int v = v2 >> 1;
            sum += (float)V[(size_t)(u * 64 + v) * RPAT + (t * 4 + s) * 128 + c];
        }
    }
    ybTpb[(size_t)(yy + 8) * ROWS + (c >> 3) * 1152 + (xx + 8) * 8 + (c & 7)] = (f16)(0.25f * sum);
}

// ---------------------------------------------------------------------------
// Wt[g][tap][oc][c] fp16 from conv_w (4,16,128,3,3) fp32
// NOTE: 73,728 ELEMENTS = 147,456 BYTES (layout must reserve bytes!)
__global__ __launch_bounds__(256) void prep_w(const float* __restrict__ cw,
                                              f16* __restrict__ Wt) {
    int idx = blockIdx.x * 256 + threadIdx.x;
    if (idx >= 4 * 9 * 16 * 128) return;
    int g = idx / 18432, rem = idx % 18432;
    int tap = rem >> 11, oc = (rem >> 7) & 15, c = rem & 127;
    Wt[idx] = (f16)cw[(((g * 16 + oc) * 128 + c) * 9) + tap];
}

// ---------------------------------------------------------------------------
// Tap-decomposed implicit-GEMM grouped dilated conv via MFMA (fp16).
// Proven R5 structure: each wave computes TWO y-rows (4 independent chains).
__global__ __launch_bounds__(256, 4) void final_conv_mfma(const f16* __restrict__ ybTp,
                                                          const f16* __restrict__ Wt,
                                                          const float* __restrict__ cb,
                                                          float* __restrict__ out) {
    int id = blockIdx.x;            // 0..1023
    int p = id & 7;
    int b = p >> 1, yhalf = p & 1;
    int rest = id >> 3;             // 0..127
    int g = rest >> 5;              // 0..3
    int y = yhalf * 64 + (rest & 31) * 2;   // rows y, y+1
    int tid = threadIdx.x, w = tid >> 6, lane = tid & 63;
    int xbase = w * 32;
    int r = 1 << g;                 // RATES = 1,2,4,8
    int m = lane & 15, q = lane >> 4;
    const f16* yB0 = ybTp + (size_t)b * PPAD * 128
                   + (size_t)(y + 8) * ROWS + q * 1152 + (xbase + m + 8) * 8;
    const f16* Wg = Wt + g * 18432 + m * 128 + q * 8;

    f32x4 acc00 = (f32x4){0.f, 0.f, 0.f, 0.f};
    f32x4 acc01 = (f32x4){0.f, 0.f, 0.f, 0.f};
    f32x4 acc10 = (f32x4){0.f, 0.f, 0.f, 0.f};
    f32x4 acc11 = (f32x4){0.f, 0.f, 0.f, 0.f};

#pragma unroll
    for (int tap = 0; tap < 9; ++tap) {
        int dy = (tap / 3 - 1) * r, dx = (tap % 3 - 1) * r;
        const f16* rb0 = yB0 + (ptrdiff_t)dy * ROWS + (ptrdiff_t)dx * 8;
        const f16* rb1 = rb0 + ROWS;
        const f16* wrow = Wg + tap * 2048;
        f16x8 bf[4];
#pragma unroll
        for (int ks = 0; ks < 4; ++ks) bf[ks] = *(const f16x8*)(wrow + ks * 32);
        f16x8 a00[4], a01[4], a10[4], a11[4];
#pragma unroll
        for (int ks = 0; ks < 4; ++ks) {
            a00[ks] = *(const f16x8*)(rb0 + ks * 4608);
            a01[ks] = *(const f16x8*)(rb0 + ks * 4608 + 128);
            a10[ks] = *(const f16x8*)(rb1 + ks * 4608);
            a11[ks] = *(const f16x8*)(rb1 + ks * 4608 + 128);
        }
#pragma unroll
        for (int ks = 0; ks < 4; ++ks) {
            acc00 = __builtin_amdgcn_mfma_f32_16x16x32_f16(a00[ks], bf[ks], acc00, 0, 0, 0);
            acc01 = __builtin_amdgcn_mfma_f32_16x16x32_f16(a01[ks], bf[ks], acc01, 0, 0, 0);
            acc10 = __builtin_amdgcn_mfma_f32_16x16x32_f16(a10[ks], bf[ks], acc10, 0, 0, 0);
            acc11 = __builtin_amdgcn_mfma_f32_16x16x32_f16(a11[ks], bf[ks], acc11, 0, 0, 0);
        }
    }

    float bias = cb[g * 16 + m];
    float* orow0 = out + ((size_t)(b * 64 + g * 16 + m)) * 16384 + (size_t)y * 128;
    float* orow1 = orow0 + 128;
#pragma unroll
    for (int ri = 0; ri < 4; ++ri) {
        orow0[xbase + q * 4 + ri]      = fmaxf(acc00[ri] + bias, 0.f);
        orow0[xbase + 16 + q * 4 + ri] = fmaxf(acc01[ri] + bias, 0.f);
        orow1[xbase + q * 4 + ri]      = fmaxf(acc10[ri] + bias, 0.f);
        orow1[xbase + 16 + q * 4 + ri] = fmaxf(acc11[ri] + bias, 0.f);
    }
}

// ---------------------------------------------------------------------------
extern "C" void kernel_launch(void* const* d_in, const int* in_sizes, int n_in,
                              void* d_out, int out_size, void* d_ws, size_t ws_size,
                              hipStream_t stream) {
    const float* x1 = (const float*)d_in[0];        // (4,128,128,128)
    const float* x2 = (const float*)d_in[1];        // (4,64,64,64)
    const float* mask = (const float*)d_in[2];      // (4,1,128,128)
    const float* mask_all = (const float*)d_in[3];  // (4,1,64,64)
    const float* conv_w = (const float*)d_in[4];    // (4,16,128,3,3)
    const float* conv_b = (const float*)d_in[5];    // (4,16)
    float* out = (float*)d_out;                     // (4,64,128,128)

    char* ws = (char*)d_ws;
    f16*   Ph4   = (f16*)  (ws + 0);            // 20,971,520 B (4 x 4096 x 640)
    float* rnorm = (float*)(ws + 20971520);     //     65,536 B (4 batches)
    int*   cidx  = (int*)  (ws + 21037056);     //     69,632 B (4 batches)
    int*   nk    = (int*)  (ws + 21106688);     //         32 B (pad to 21,106,944)
    f16*   Wt    = (f16*)  (ws + 21106944);     //    147,456 B (73,728 f16 elems)
    f16*   S     = (f16*)  (ws + 21254400);     // 33,554,432 B (per-batch reuse)
    f16*   V     = (f16*)  (ws + 54808832);     // 16,777,216 B
    f16*   Ah    = (f16*)  (ws + 71586048);     // 33,554,432 B
    f16*   Rt    = (f16*)  (ws + 105140480);    // 16,777,216 B
    f16*   ybTp  = (f16*)  (ws + 121917696);    // 21,233,664 B (ends 143,151,360)

    prep_w<<<288, 256, 0, stream>>>(conv_w, Wt);
    compact_mask_all<<<4, 256, 0, stream>>>(mask, cidx, nk);
    zero_halo<<<5184, 256, 0, stream>>>(ybTp);
    build_P_norm<<<16384, 64, 0, stream>>>(x2, Ph4, rnorm);   // all 4 batches
    for (int b = 0; b < 4; ++b) {
        const float* x1b = x1 + (size_t)b * 128 * 16384;
        const int* cb_idx = cidx + b * 4352;
        const int* nkb = nk + b * 2;
        const f16* Phb = Ph4 + (size_t)b * 4096 * KPATP;
        gemm_score_mfma<<<dim3(32, 32), 256, 0, stream>>>(Phb, cb_idx, rnorm + b * 4096, nkb, S);
        softmax_mask<<<4096, 256, 0, stream>>>(S, nkb, mask_all + (size_t)b * 4096, Ah);
        build_Rt<<<32768, 256, 0, stream>>>(x1b, cb_idx, nkb, Rt);
        gemm_deconv128<<<512, 256, 0, stream>>>(Ah, Rt, nkb, V);
        reconstruct<<<8192, 256, 0, stream>>>(V, ybTp + (size_t)b * PPAD * 128);
    }
    final_conv_mfma<<<1024, 256, 0, stream>>>(ybTp, Wt, conv_b, out);
}

// Round 14
// 596.817 us; speedup vs baseline: 1.0106x; 1.0106x over previous
//
#include <hip/hip_runtime.h>
#include <math.h>

typedef _Float16 f16;
typedef __attribute__((ext_vector_type(8))) _Float16 f16x8;
typedef __attribute__((ext_vector_type(4))) float f32x4;
typedef __attribute__((ext_vector_type(16))) float f32x16;

#define LPOS 4096      // 64*64 positions / patches
#define KPAT 576       // 64ch * 3*3 patch
#define KPATP 640      // Ph row stride, padded to 10 x 64-K-tiles (tail zeroed)
#define RPAT 2048      // 128ch * 4*4 raw patch
#define PPAD 20736     // 144*144 padded positions for ybT
#define ROWS 18432     // elems per padded row: 16 chunks * 144 x * 8

#define GLDS(g, l) __builtin_amdgcn_global_load_lds( \
    (const __attribute__((address_space(1))) void*)(g), \
    (__attribute__((address_space(3))) void*)(l), 16, 0, 0)

// ---------------------------------------------------------------------------
// Batched: Ph4[b][pos][640] = fp16 3x3x64 patches of x2[b] (zero pad 1),
// cols 576..639 zeroed; rnorm4[b][pos]
__global__ __launch_bounds__(64) void build_P_norm(const float* __restrict__ x2,
                                                   f16* __restrict__ Ph4,
                                                   float* __restrict__ rnorm4) {
    int bid = blockIdx.x;
    int b = bid >> 12, pos = bid & 4095;
    const float* x2b = x2 + (size_t)b * 64 * 4096;
    f16* Ph = Ph4 + (size_t)b * 4096 * KPATP;
    float* rnorm = rnorm4 + b * 4096;
    int u = pos >> 6, v = pos & 63;
    int tid = threadIdx.x;
    float ss = 0.f;
    for (int k = tid; k < KPAT; k += 64) {
        int c = k / 9, r9 = k % 9;
        int di = r9 / 3, dj = r9 % 3;
        int yy = u + di - 1, xx = v + dj - 1;
        float val = 0.f;
        if (yy >= 0 && yy < 64 && xx >= 0 && xx < 64)
            val = x2b[c * 4096 + yy * 64 + xx];
        Ph[pos * KPATP + k] = (f16)val;
        ss += val * val;
    }
    Ph[pos * KPATP + KPAT + tid] = (f16)0.f;   // zero the 64-wide K-pad tail
#pragma unroll
    for (int off = 32; off; off >>= 1) ss += __shfl_xor(ss, off, 64);
    if (tid == 0) rnorm[pos] = 1.f / fmaxf(sqrtf(ss), 1e-4f);
}

// ---------------------------------------------------------------------------
// All 4 batches in one launch: block b compacts mask[b] -> cidx[b], nk[b]
// nk[0] = nkeep, nk[1] = nkeep padded to 128 (deconv needs even 64-tiles)
__global__ __launch_bounds__(256) void compact_mask_all(const float* __restrict__ mask,
                                                        int* __restrict__ cidx_all,
                                                        int* __restrict__ nk_all) {
    int b = blockIdx.x;
    const float* maskb = mask + (size_t)b * 16384;
    int* cidx = cidx_all + b * 4352;
    int* nk = nk_all + b * 2;
    int tid = threadIdx.x;
    int keep[16];
    int cnt = 0;
#pragma unroll
    for (int e = 0; e < 16; ++e) {
        int pos = tid * 16 + e;
        int pu = pos >> 6, pv = pos & 63;
        float s = 0.f;
        for (int t = 0; t < 4; ++t)
            for (int w = 0; w < 4; ++w) {
                int yy = 2 * pu - 1 + t, xx = 2 * pv - 1 + w;
                if (yy >= 0 && yy < 128 && xx >= 0 && xx < 128)
                    s += maskb[yy * 128 + xx];
            }
        keep[e] = (s == 0.f) ? 1 : 0;
        cnt += keep[e];
    }
    __shared__ int ps[256];
    ps[tid] = cnt;
    __syncthreads();
    for (int off = 1; off < 256; off <<= 1) {
        int v = (tid >= off) ? ps[tid - off] : 0;
        __syncthreads();
        ps[tid] += v;
        __syncthreads();
    }
    int total = ps[255];
    int base = ps[tid] - cnt;   // exclusive prefix
#pragma unroll
    for (int e = 0; e < 16; ++e)
        if (keep[e]) cidx[base++] = tid * 16 + e;
    for (int i = total + tid; i < 4352; i += 256) cidx[i] = 0;
    if (tid == 0) { nk[0] = total; nk[1] = (total + 127) & ~127; }
}

// ---------------------------------------------------------------------------
// Zero the 8-wide halo of the padded chunk-major ybT buffer (all 4 batches)
__global__ __launch_bounds__(256) void zero_halo(f16* __restrict__ ybTp) {
    int idx = blockIdx.x * 256 + threadIdx.x;
    int b = idx / 331776; if (b >= 4) return;
    int rem = idx % 331776;                     // 144*144*16
    int q = rem & 15, pos = rem >> 4;
    int yy = pos / 144, xx = pos % 144;
    if (yy >= 8 && yy < 136 && xx >= 8 && xx < 136) return;
    *(f16x8*)(ybTp + (size_t)b * PPAD * 128 + (size_t)yy * ROWS + q * 1152 + xx * 8) = (f16x8){};
}

// ---------------------------------------------------------------------------
// SCORE GEMM on the R2-PROVEN fallback-deconv skeleton (deterministic:
// single-buffered LDS, BK=64, 2 __syncthreads per K-step, NO hand vmcnt):
//   S[m][col] = (Ph[m] . Ph[cidx[col]]) * rnorm[cidx[col]], fp16 out.
//   grid dim3(32 nt, 32 mt), early-exit on col tiles beyond nkeep.
//   256 thr = 4 waves (2M x 2N), per-wave 64x64 via 2x2 of 32x32x16 MFMA.
//   K = 640 padded (10 x BK=64; pad tile is zeros -> contributes 0).
//   LDS 32KB -> ~3 blocks/CU co-resident (m114 cross-block overlap).
//   Swizzle chunk ^= row&7 (pre-swizzled global src, linear GLDS dest,
//   swizzled read addr). Only addressing differs from the proven skeleton:
//   A row stride KPATP; B rows gathered via cidx (hoisted pointers,
//   pattern proven green in R10's gemm_score_mfma).
__global__ __launch_bounds__(256) void gemm_score64(const f16* __restrict__ Ph,
                                                    const int* __restrict__ cidx,
                                                    const float* __restrict__ rnorm,
                                                    const int* __restrict__ nk,
                                                    f16* __restrict__ S) {
    __shared__ f16 Ash[128 * 64], Bsh[128 * 64];
    int n0 = blockIdx.x * 128;
    if (n0 >= nk[0]) return;    // fully-masked column tile (block-uniform)
    int m0 = blockIdx.y * 128;

    int tid = threadIdx.x;
    int w = tid >> 6, lane = tid & 63;
    int wy = w >> 1, wx = w & 1;
    f32x16 acc[2][2];
#pragma unroll
    for (int mt = 0; mt < 2; ++mt)
#pragma unroll
        for (int nt = 0; nt < 2; ++nt)
#pragma unroll
            for (int e = 0; e < 16; ++e) acc[mt][nt][e] = 0.f;

    int srow = lane >> 3;          // 0..7 staging row within instr
    int cblk = lane & 7;           // 0..7 LDS slot (16B chunk) within row
    int scol = (cblk ^ srow) * 8;  // swizzled global chunk (f(row) = row&7 = srow)
    int l31 = lane & 31, kh2 = lane >> 5;
    int f7 = l31 & 7;              // read-side f(row)
    int arow[2], brow[2];
#pragma unroll
    for (int i = 0; i < 2; ++i) {
        arow[i] = wy * 64 + i * 32 + l31;
        brow[i] = wx * 64 + i * 32 + l31;
    }
    // hoisted per-thread source pointers (4 staging units of 32 rows)
    const f16* Asrc[4]; const f16* Bsrc[4]; int ldso[4];
#pragma unroll
    for (int i = 0; i < 4; ++i) {
        int row = w * 32 + i * 8 + srow;
        ldso[i] = row * 64 + cblk * 8;
        Asrc[i] = Ph + (size_t)(m0 + row) * KPATP + scol;
        Bsrc[i] = Ph + (size_t)cidx[n0 + row] * KPATP + scol;
    }
    for (int k0 = 0; k0 < KPATP; k0 += 64) {
#pragma unroll
        for (int i = 0; i < 4; ++i) {
            GLDS(Asrc[i] + k0, Ash + ldso[i]);
            GLDS(Bsrc[i] + k0, Bsh + ldso[i]);
        }
        __syncthreads();
#pragma unroll
        for (int kh = 0; kh < 4; ++kh) {
            int slot = (kh * 2 + kh2) ^ f7;
            f16x8 va[2], vb[2];
#pragma unroll
            for (int i = 0; i < 2; ++i) {
                va[i] = *(const f16x8*)&Ash[arow[i] * 64 + slot * 8];
                vb[i] = *(const f16x8*)&Bsh[brow[i] * 64 + slot * 8];
            }
#pragma unroll
            for (int mt = 0; mt < 2; ++mt)
#pragma unroll
                for (int nt = 0; nt < 2; ++nt)
                    acc[mt][nt] = __builtin_amdgcn_mfma_f32_32x32x16_f16(va[mt], vb[nt], acc[mt][nt], 0, 0, 0);
        }
        __syncthreads();
    }
    int rbase = 4 * kh2;
#pragma unroll
    for (int mt = 0; mt < 2; ++mt)
#pragma unroll
        for (int nt = 0; nt < 2; ++nt) {
            int col = n0 + wx * 64 + nt * 32 + l31;
            float rn = rnorm[cidx[col]];
#pragma unroll
            for (int rg = 0; rg < 16; ++rg) {
                int row = m0 + wy * 64 + mt * 32 + (rg & 3) + 8 * (rg >> 2) + rbase;
                S[(size_t)row * LPOS + col] = (f16)(acc[mt][nt][rg] * rn);
            }
        }
}

// ---------------------------------------------------------------------------
// Masked softmax over compacted columns (f16x8 reads/writes).
// Skips S reads for whole 8-groups beyond kpad (always-masked anyway).
__global__ __launch_bounds__(256) void softmax_mask(const f16* __restrict__ S,
                                                    const int* __restrict__ nk,
                                                    const float* __restrict__ mab,
                                                    f16* __restrict__ Ah) {
    int pos = blockIdx.x;
    int tid = threadIdx.x;
    int nkeep = nk[0], kpad = nk[1];
    float ma = mab[pos];
    float sc = 10.0f * ma;
    const f16* Srow = S + (size_t)pos * LPOS;
    float v[16];
    float vmax = (nkeep < LPOS) ? 0.f : -3.0e38f;
#pragma unroll
    for (int i = 0; i < 2; ++i) {
        int jb = (tid + i * 256) * 8;
        if (jb < kpad) {
            f16x8 x8 = *(const f16x8*)(Srow + jb);
#pragma unroll
            for (int e = 0; e < 8; ++e) {
                float x = (jb + e < nkeep) ? (float)x8[e] * sc : -3.0e38f;
                v[i * 8 + e] = x;
                vmax = fmaxf(vmax, x);
            }
        } else {
#pragma unroll
            for (int e = 0; e < 8; ++e) v[i * 8 + e] = -3.0e38f;
        }
    }
#pragma unroll
    for (int off = 32; off; off >>= 1) vmax = fmaxf(vmax, __shfl_xor(vmax, off, 64));
    __shared__ float sred[4];
    int wid = tid >> 6;
    if ((tid & 63) == 0) sred[wid] = vmax;
    __syncthreads();
    vmax = fmaxf(fmaxf(sred[0], sred[1]), fmaxf(sred[2], sred[3]));
    __syncthreads();
    float ssum = 0.f;
#pragma unroll
    for (int i = 0; i < 16; ++i) {
        float e = (v[i] > -1.0e37f) ? __expf(v[i] - vmax) : 0.f;
        v[i] = e;
        ssum += e;
    }
#pragma unroll
    for (int off = 32; off; off >>= 1) ssum += __shfl_xor(ssum, off, 64);
    if ((tid & 63) == 0) sred[wid] = ssum;
    __syncthreads();
    float total = sred[0] + sred[1] + sred[2] + sred[3]
                + (float)(LPOS - nkeep) * __expf(-vmax);
    float inv = 1.f / total;
#pragma unroll
    for (int i = 0; i < 2; ++i) {
        int jb = (tid + i * 256) * 8;
        if (jb >= kpad) continue;
        f16x8 h;
#pragma unroll
        for (int e = 0; e < 8; ++e)
            h[e] = (jb + e < nkeep) ? (f16)(v[i * 8 + e] * inv * ma) : (f16)0.f;
        *(f16x8*)(Ah + (size_t)pos * LPOS + jb) = h;
    }
}

// ---------------------------------------------------------------------------
// Rt[n][j] fp16, n = (t*4+s)*128 + c, patch p = cidx[j] (compacted gather)
__global__ __launch_bounds__(256) void build_Rt(const float* __restrict__ x1b,
                                                const int* __restrict__ cidx,
                                                const int* __restrict__ nk,
                                                f16* __restrict__ Rt) {
    int idx = blockIdx.x * 256 + threadIdx.x;   // n*4096 + j
    int j = idx & 4095, n = idx >> 12;
    if (j >= nk[1]) return;
    int p = cidx[j];
    int pu = p >> 6, pv = p & 63;
    int t = (n >> 9) & 3, s = (n >> 7) & 3, c = n & 127;
    int yy = 2 * pu - 1 + t, xx = 2 * pv - 1 + s;
    float val = 0.f;
    if (yy >= 0 && yy < 128 && xx >= 0 && xx < 128)
        val = x1b[c * 16384 + yy * 128 + xx];
    Rt[idx] = (f16)val;
}

// ---------------------------------------------------------------------------
// 128x128 8-PHASE DECONV, 2 blocks/CU (proven R7): V = Ah . Rt^T, fp16 out.
__global__ __launch_bounds__(256, 2) void gemm_deconv128(const f16* __restrict__ A,
                                                         const f16* __restrict__ Bt,
                                                         const int* __restrict__ nk,
                                                         f16* __restrict__ V) {
    __shared__ __align__(16) f16 L[32768];     // 65536 B
    int id = blockIdx.x;
    int orig = (id & 7) * 64 + (id >> 3);      // XCD-contiguous chunks
    int mt = orig >> 4, nt = orig & 15;
    int m0 = mt * 128, n0 = nt * 128;
    int kpad = nk[1];
    int ntile = kpad >> 6;                     // even (128-padded)
    int NI = ntile >> 1;

    int tid = threadIdx.x;
    int lane = tid & 63, wid = tid >> 6;
    int wy = wid >> 1, wx = wid & 1;           // 2M x 2N wave grid
    int r16 = lane & 15, q = lane >> 4;

    int sr = tid >> 3, sc = tid & 7;
    int colo = (sc ^ (sr & 7)) * 8;            // pre-swizzled global chunk
    const f16* pA = A  + (size_t)(m0 + sr) * 4096 + colo;
    const f16* pB = Bt + (size_t)(n0 + sr) * 4096 + colo;

    int s3 = r16 & 7;
    int qs = (q ^ (s3 & 3)) * 8;
    int kf = s3 >> 2;
    const f16* aB = L + (wy * 64 + r16) * 64 + qs;
    const f16* bB = L + 8192 + (wx * 64 + r16) * 64 + qs;

    f32x4 acc[4][4];
#pragma unroll
    for (int i = 0; i < 4; ++i)
#pragma unroll
        for (int j = 0; j < 4; ++j) acc[i][j] = (f32x4){0.f, 0.f, 0.f, 0.f};

    f16x8 af[2][2], b0[2][2], bc[2][2];

#define STGA(bf, u, kt) do { \
    int kk_ = ((kt) < ntile) ? (kt) * 64 : 0; \
    GLDS(pA + (size_t)(u) * 131072 + kk_, L + (bf) * 16384 + (u) * 2048 + tid * 8); \
} while (0)
#define STGB(bf, u, kt) do { \
    int kk_ = ((kt) < ntile) ? (kt) * 64 : 0; \
    GLDS(pB + (size_t)(u) * 131072 + kk_, L + (bf) * 16384 + 8192 + (u) * 2048 + tid * 8); \
} while (0)
#define RDA(bf, msub) do { \
    _Pragma("unroll") for (int mf_ = 0; mf_ < 2; ++mf_) \
    _Pragma("unroll") for (int ks_ = 0; ks_ < 2; ++ks_) \
        af[mf_][ks_] = *(const f16x8*)(aB + (bf) * 16384 + (msub) * 2048 + mf_ * 1024 + ((ks_ ^ kf) << 5)); \
} while (0)
#define RDB(dst, bf, nsub) do { \
    _Pragma("unroll") for (int nf_ = 0; nf_ < 2; ++nf_) \
    _Pragma("unroll") for (int ks_ = 0; ks_ < 2; ++ks_) \
        dst[nf_][ks_] = *(const f16x8*)(bB + (bf) * 16384 + (nsub) * 2048 + nf_ * 1024 + ((ks_ ^ kf) << 5)); \
} while (0)
#define QMM(msub, nsub, bfr) do { \
    __builtin_amdgcn_s_setprio(1); \
    _Pragma("unroll") for (int mf_ = 0; mf_ < 2; ++mf_) \
    _Pragma("unroll") for (int nf_ = 0; nf_ < 2; ++nf_) \
    _Pragma("unroll") for (int ks_ = 0; ks_ < 2; ++ks_) \
        acc[(msub) * 2 + mf_][(nsub) * 2 + nf_] = __builtin_amdgcn_mfma_f32_16x16x32_f16( \
            af[mf_][ks_], bfr[nf_][ks_], acc[(msub) * 2 + mf_][(nsub) * 2 + nf_], 0, 0, 0); \
    __builtin_amdgcn_s_setprio(0); \
} while (0)
#define BAR()  __builtin_amdgcn_s_barrier()
#define VMW4() asm volatile("s_waitcnt vmcnt(4)" ::: "memory")

    STGB(0, 0, 0); STGB(0, 1, 0); STGB(0, 2, 0); STGB(0, 3, 0);
    STGA(0, 0, 0); STGA(0, 1, 0); STGA(0, 2, 0); STGA(0, 3, 0);
    STGB(1, 0, 1); STGB(1, 1, 1); STGB(1, 2, 1); STGB(1, 3, 1);
    VMW4(); BAR();

    for (int i = 0; i < NI; ++i) {
        int kt1 = 2 * i + 1, kt2 = 2 * i + 2, kt3 = 2 * i + 3;
        RDA(0, 0); RDB(b0, 0, 0);
        STGA(1, 0, kt1); STGA(1, 1, kt1);
        BAR(); QMM(0, 0, b0); BAR();
        RDB(bc, 0, 1);
        STGA(1, 2, kt1); STGA(1, 3, kt1);
        BAR(); QMM(0, 1, bc); BAR();
        RDA(0, 1);
        STGB(0, 0, kt2); STGB(0, 1, kt2);
        BAR(); QMM(1, 1, bc); BAR();
        STGB(0, 2, kt2); STGB(0, 3, kt2);
        BAR(); QMM(1, 0, b0);
        VMW4(); BAR();
        RDA(1, 0); RDB(b0, 1, 0);
        STGA(0, 0, kt2); STGA(0, 1, kt2);
        BAR(); QMM(0, 0, b0); BAR();
        RDB(bc, 1, 1);
        STGA(0, 2, kt2); STGA(0, 3, kt2);
        BAR(); QMM(0, 1, bc); BAR();
        RDA(1, 1);
        STGB(1, 0, kt3); STGB(1, 1, kt3);
        BAR(); QMM(1, 1, bc); BAR();
        STGB(1, 2, kt3); STGB(1, 3, kt3);
        BAR(); QMM(1, 0, b0);
        VMW4(); BAR();
    }

    asm volatile("s_waitcnt vmcnt(0)" ::: "memory");

#pragma unroll
    for (int mi = 0; mi < 4; ++mi) {
        int row = m0 + wy * 64 + mi * 16 + q * 4;
#pragma unroll
        for (int ni = 0; ni < 4; ++ni) {
            int col = n0 + wx * 64 + ni * 16 + r16;
#pragma unroll
            for (int g = 0; g < 4; ++g)
                V[(size_t)(row + g) * RPAT + col] = (f16)acc[mi][ni][g];
        }
    }
#undef STGA
#undef STGB
#undef RDA
#undef RDB
#undef QMM
#undef BAR
#undef VMW4
}

// ---------------------------------------------------------------------------
// reconstruct -> chunk-major padded layout:
// ybTp[b][yy+8][q=c>>3][xx+8][c&7] = 0.25 * sum over valid taps of V
__global__ __launch_bounds__(256) void reconstruct(const f16* __restrict__ V,
                                                   f16* __restrict__ ybTpb) {
    int idx = blockIdx.x * 256 + threadIdx.x;   // p*128 + c
    int c = idx & 127, p = idx >> 7;
    int xx = p & 127, yy = p >> 7;
    float sum = 0.f;
    int tby = (yy & 1) ? 0 : 1;
    int tbx = (xx & 1) ? 0 : 1;
#pragma unroll
    for (int dt = 0; dt < 2; ++dt) {
        int t = tby + 2 * dt;
        int u2 = yy + 1 - t;
        if (u2 < 0 || u2 >= 128) continue;
        int u = u2 >> 1;
#pragma unroll
        for (int ds = 0; ds < 2; ++ds) {
            int s = tbx + 2 * ds;
            int v2 = xx + 1 - s;
            if (v2 < 0 || v2 >= 128) continue;
            int v = v2 >> 1;
            sum += (float)V[(size_t)(u * 64 + v) * RPAT + (t * 4 + s) * 128 + c];
        }
    }
    ybTpb[(size_t)(yy + 8) * ROWS + (c >> 3) * 1152 + (xx + 8) * 8 + (c & 7)] = (f16)(0.25f * sum);
}

// ---------------------------------------------------------------------------
// Wt[g][tap][oc][c] fp16 from conv_w (4,16,128,3,3) fp32
// NOTE: 73,728 ELEMENTS = 147,456 BYTES (layout must reserve bytes!)
__global__ __launch_bounds__(256) void prep_w(const float* __restrict__ cw,
                                              f16* __restrict__ Wt) {
    int idx = blockIdx.x * 256 + threadIdx.x;
    if (idx >= 4 * 9 * 16 * 128) return;
    int g = idx / 18432, rem = idx % 18432;
    int tap = rem >> 11, oc = (rem >> 7) & 15, c = rem & 127;
    Wt[idx] = (f16)cw[(((g * 16 + oc) * 128 + c) * 9) + tap];
}

// ---------------------------------------------------------------------------
// Tap-decomposed implicit-GEMM grouped dilated conv via MFMA (fp16).
// Proven R5 structure: each wave computes TWO y-rows (4 independent chains).
__global__ __launch_bounds__(256, 4) void final_conv_mfma(const f16* __restrict__ ybTp,
                                                          const f16* __restrict__ Wt,
                                                          const float* __restrict__ cb,
                                                          float* __restrict__ out) {
    int id = blockIdx.x;            // 0..1023
    int p = id & 7;
    int b = p >> 1, yhalf = p & 1;
    int rest = id >> 3;             // 0..127
    int g = rest >> 5;              // 0..3
    int y = yhalf * 64 + (rest & 31) * 2;   // rows y, y+1
    int tid = threadIdx.x, w = tid >> 6, lane = tid & 63;
    int xbase = w * 32;
    int r = 1 << g;                 // RATES = 1,2,4,8
    int m = lane & 15, q = lane >> 4;
    const f16* yB0 = ybTp + (size_t)b * PPAD * 128
                   + (size_t)(y + 8) * ROWS + q * 1152 + (xbase + m + 8) * 8;
    const f16* Wg = Wt + g * 18432 + m * 128 + q * 8;

    f32x4 acc00 = (f32x4){0.f, 0.f, 0.f, 0.f};
    f32x4 acc01 = (f32x4){0.f, 0.f, 0.f, 0.f};
    f32x4 acc10 = (f32x4){0.f, 0.f, 0.f, 0.f};
    f32x4 acc11 = (f32x4){0.f, 0.f, 0.f, 0.f};

#pragma unroll
    for (int tap = 0; tap < 9; ++tap) {
        int dy = (tap / 3 - 1) * r, dx = (tap % 3 - 1) * r;
        const f16* rb0 = yB0 + (ptrdiff_t)dy * ROWS + (ptrdiff_t)dx * 8;
        const f16* rb1 = rb0 + ROWS;
        const f16* wrow = Wg + tap * 2048;
        f16x8 bf[4];
#pragma unroll
        for (int ks = 0; ks < 4; ++ks) bf[ks] = *(const f16x8*)(wrow + ks * 32);
        f16x8 a00[4], a01[4], a10[4], a11[4];
#pragma unroll
        for (int ks = 0; ks < 4; ++ks) {
            a00[ks] = *(const f16x8*)(rb0 + ks * 4608);
            a01[ks] = *(const f16x8*)(rb0 + ks * 4608 + 128);
            a10[ks] = *(const f16x8*)(rb1 + ks * 4608);
            a11[ks] = *(const f16x8*)(rb1 + ks * 4608 + 128);
        }
#pragma unroll
        for (int ks = 0; ks < 4; ++ks) {
            acc00 = __builtin_amdgcn_mfma_f32_16x16x32_f16(a00[ks], bf[ks], acc00, 0, 0, 0);
            acc01 = __builtin_amdgcn_mfma_f32_16x16x32_f16(a01[ks], bf[ks], acc01, 0, 0, 0);
            acc10 = __builtin_amdgcn_mfma_f32_16x16x32_f16(a10[ks], bf[ks], acc10, 0, 0, 0);
            acc11 = __builtin_amdgcn_mfma_f32_16x16x32_f16(a11[ks], bf[ks], acc11, 0, 0, 0);
        }
    }

    float bias = cb[g * 16 + m];
    float* orow0 = out + ((size_t)(b * 64 + g * 16 + m)) * 16384 + (size_t)y * 128;
    float* orow1 = orow0 + 128;
#pragma unroll
    for (int ri = 0; ri < 4; ++ri) {
        orow0[xbase + q * 4 + ri]      = fmaxf(acc00[ri] + bias, 0.f);
        orow0[xbase + 16 + q * 4 + ri] = fmaxf(acc01[ri] + bias, 0.f);
        orow1[xbase + q * 4 + ri]      = fmaxf(acc10[ri] + bias, 0.f);
        orow1[xbase + 16 + q * 4 + ri] = fmaxf(acc11[ri] + bias, 0.f);
    }
}

// ---------------------------------------------------------------------------
extern "C" void kernel_launch(void* const* d_in, const int* in_sizes, int n_in,
                              void* d_out, int out_size, void* d_ws, size_t ws_size,
                              hipStream_t stream) {
    const float* x1 = (const float*)d_in[0];        // (4,128,128,128)
    const float* x2 = (const float*)d_in[1];        // (4,64,64,64)
    const float* mask = (const float*)d_in[2];      // (4,1,128,128)
    const float* mask_all = (const float*)d_in[3];  // (4,1,64,64)
    const float* conv_w = (const float*)d_in[4];    // (4,16,128,3,3)
    const float* conv_b = (const float*)d_in[5];    // (4,16)
    float* out = (float*)d_out;                     // (4,64,128,128)

    char* ws = (char*)d_ws;
    f16*   Ph4   = (f16*)  (ws + 0);            // 20,971,520 B (4 x 4096 x 640)
    float* rnorm = (float*)(ws + 20971520);     //     65,536 B (4 batches)
    int*   cidx  = (int*)  (ws + 21037056);     //     69,632 B (4 batches)
    int*   nk    = (int*)  (ws + 21106688);     //         32 B (pad to 21,106,944)
    f16*   Wt    = (f16*)  (ws + 21106944);     //    147,456 B (73,728 f16 elems)
    f16*   S     = (f16*)  (ws + 21254400);     // 33,554,432 B (per-batch reuse)
    f16*   V     = (f16*)  (ws + 54808832);     // 16,777,216 B
    f16*   Ah    = (f16*)  (ws + 71586048);     // 33,554,432 B
    f16*   Rt    = (f16*)  (ws + 105140480);    // 16,777,216 B
    f16*   ybTp  = (f16*)  (ws + 121917696);    // 21,233,664 B (ends 143,151,360)

    prep_w<<<288, 256, 0, stream>>>(conv_w, Wt);
    compact_mask_all<<<4, 256, 0, stream>>>(mask, cidx, nk);
    zero_halo<<<5184, 256, 0, stream>>>(ybTp);
    build_P_norm<<<16384, 64, 0, stream>>>(x2, Ph4, rnorm);   // all 4 batches
    for (int b = 0; b < 4; ++b) {
        const float* x1b = x1 + (size_t)b * 128 * 16384;
        const int* cb_idx = cidx + b * 4352;
        const int* nkb = nk + b * 2;
        const f16* Phb = Ph4 + (size_t)b * 4096 * KPATP;
        gemm_score64<<<dim3(32, 32), 256, 0, stream>>>(Phb, cb_idx, rnorm + b * 4096, nkb, S);
        softmax_mask<<<4096, 256, 0, stream>>>(S, nkb, mask_all + (size_t)b * 4096, Ah);
        build_Rt<<<32768, 256, 0, stream>>>(x1b, cb_idx, nkb, Rt);
        gemm_deconv128<<<512, 256, 0, stream>>>(Ah, Rt, nkb, V);
        reconstruct<<<8192, 256, 0, stream>>>(V, ybTp + (size_t)b * PPAD * 128);
    }
    final_conv_mfma<<<1024, 256, 0, stream>>>(ybTp, Wt, conv_b, out);
}

// Round 16
// 573.194 us; speedup vs baseline: 1.0522x; 1.0412x over previous
//
#include <hip/hip_runtime.h>
#include <math.h>

typedef _Float16 f16;
typedef __attribute__((ext_vector_type(8))) _Float16 f16x8;
typedef __attribute__((ext_vector_type(4))) float f32x4;
typedef __attribute__((ext_vector_type(16))) float f32x16;

#define LPOS 4096      // 64*64 positions / patches
#define KPAT 576       // 64ch * 3*3 patch (= exactly 9 BK=64 tiles)
#define KPATP 640      // Ph row stride (256B-aligned rows; cols 576..639 zeroed)
#define RPAT 2048      // 128ch * 4*4 raw patch
#define PPAD 20736     // 144*144 padded positions for ybT
#define ROWS 18432     // elems per padded row: 16 chunks * 144 x * 8

#define GLDS(g, l) __builtin_amdgcn_global_load_lds( \
    (const __attribute__((address_space(1))) void*)(g), \
    (__attribute__((address_space(3))) void*)(l), 16, 0, 0)

// ---------------------------------------------------------------------------
// FUSED PROLOGUE (R14/R15): 4 independent prologue kernels in one launch,
// branched on blockIdx ranges. All sub-parts byte-equivalent to the proven
// standalone kernels (build_P_norm re-hosted as 4 waves/block).
//   bid [0,4096)      : build_P_norm (4 waves x 1 pos each; 16384 pos total)
//   bid [4096,4100)   : compact_mask_all (b = bid-4096)
//   bid [4100,9284)   : zero_halo
//   bid [9284,9572)   : prep_w
__global__ __launch_bounds__(256) void prologue_fused(const float* __restrict__ x2,
                                                      f16* __restrict__ Ph4,
                                                      float* __restrict__ rnorm4,
                                                      const float* __restrict__ mask,
                                                      int* __restrict__ cidx_all,
                                                      int* __restrict__ nk_all,
                                                      f16* __restrict__ ybTp,
                                                      const float* __restrict__ cw,
                                                      f16* __restrict__ Wt) {
    int bid = blockIdx.x;
    int tid = threadIdx.x;
    if (bid < 4096) {
        // ---- build_P_norm: global pos = bid*4 + wave ----
        int lane = tid & 63;
        int gp = bid * 4 + (tid >> 6);          // 0..16383
        int b = gp >> 12, pos = gp & 4095;
        const float* x2b = x2 + (size_t)b * 64 * 4096;
        f16* Ph = Ph4 + (size_t)b * 4096 * KPATP;
        float* rnorm = rnorm4 + b * 4096;
        int u = pos >> 6, v = pos & 63;
        float ss = 0.f;
        for (int k = lane; k < KPAT; k += 64) {
            int c = k / 9, r9 = k % 9;
            int di = r9 / 3, dj = r9 % 3;
            int yy = u + di - 1, xx = v + dj - 1;
            float val = 0.f;
            if (yy >= 0 && yy < 64 && xx >= 0 && xx < 64)
                val = x2b[c * 4096 + yy * 64 + xx];
            Ph[pos * KPATP + k] = (f16)val;
            ss += val * val;
        }
        Ph[pos * KPATP + KPAT + lane] = (f16)0.f;   // zero 64-wide K-pad tail
#pragma unroll
        for (int off = 32; off; off >>= 1) ss += __shfl_xor(ss, off, 64);
        if (lane == 0) rnorm[pos] = 1.f / fmaxf(sqrtf(ss), 1e-4f);
        return;
    }
    if (bid < 4100) {
        // ---- compact_mask_all ----
        int b = bid - 4096;
        const float* maskb = mask + (size_t)b * 16384;
        int* cidx = cidx_all + b * 4352;
        int* nk = nk_all + b * 2;
        int keep[16];
        int cnt = 0;
#pragma unroll
        for (int e = 0; e < 16; ++e) {
            int pos = tid * 16 + e;
            int pu = pos >> 6, pv = pos & 63;
            float s = 0.f;
            for (int t = 0; t < 4; ++t)
                for (int w = 0; w < 4; ++w) {
                    int yy = 2 * pu - 1 + t, xx = 2 * pv - 1 + w;
                    if (yy >= 0 && yy < 128 && xx >= 0 && xx < 128)
                        s += maskb[yy * 128 + xx];
                }
            keep[e] = (s == 0.f) ? 1 : 0;
            cnt += keep[e];
        }
        __shared__ int ps[256];
        ps[tid] = cnt;
        __syncthreads();
        for (int off = 1; off < 256; off <<= 1) {
            int v = (tid >= off) ? ps[tid - off] : 0;
            __syncthreads();
            ps[tid] += v;
            __syncthreads();
        }
        int total = ps[255];
        int base = ps[tid] - cnt;   // exclusive prefix
#pragma unroll
        for (int e = 0; e < 16; ++e)
            if (keep[e]) cidx[base++] = tid * 16 + e;
        for (int i = total + tid; i < 4352; i += 256) cidx[i] = 0;
        if (tid == 0) { nk[0] = total; nk[1] = (total + 127) & ~127; }
        return;
    }
    if (bid < 9284) {
        // ---- zero_halo ----
        int idx = (bid - 4100) * 256 + tid;
        int b = idx / 331776; if (b >= 4) return;
        int rem = idx % 331776;                 // 144*144*16
        int q = rem & 15, pos = rem >> 4;
        int yy = pos / 144, xx = pos % 144;
        if (yy >= 8 && yy < 136 && xx >= 8 && xx < 136) return;
        *(f16x8*)(ybTp + (size_t)b * PPAD * 128 + (size_t)yy * ROWS + q * 1152 + xx * 8) = (f16x8){};
        return;
    }
    {
        // ---- prep_w  (73,728 ELEMENTS = 147,456 BYTES in workspace!) ----
        int idx = (bid - 9284) * 256 + tid;
        if (idx >= 4 * 9 * 16 * 128) return;
        int g = idx / 18432, rem = idx % 18432;
        int tap = rem >> 11, oc = (rem >> 7) & 15, c = rem & 127;
        Wt[idx] = (f16)cw[(((g * 16 + oc) * 128 + c) * 9) + tap];
    }
}

// ---------------------------------------------------------------------------
// SCORE GEMM on the R2-proven fallback skeleton (deterministic: single-buffer
// LDS, BK=64, 2 __syncthreads per K-step, NO hand vmcnt). R14: K loop runs
// the 9 real tiles only (576 = 9*64); the all-zero pad tile is skipped.
__global__ __launch_bounds__(256) void gemm_score64(const f16* __restrict__ Ph,
                                                    const int* __restrict__ cidx,
                                                    const float* __restrict__ rnorm,
                                                    const int* __restrict__ nk,
                                                    f16* __restrict__ S) {
    __shared__ f16 Ash[128 * 64], Bsh[128 * 64];
    int n0 = blockIdx.x * 128;
    if (n0 >= nk[0]) return;    // fully-masked column tile (block-uniform)
    int m0 = blockIdx.y * 128;

    int tid = threadIdx.x;
    int w = tid >> 6, lane = tid & 63;
    int wy = w >> 1, wx = w & 1;
    f32x16 acc[2][2];
#pragma unroll
    for (int mt = 0; mt < 2; ++mt)
#pragma unroll
        for (int nt = 0; nt < 2; ++nt)
#pragma unroll
            for (int e = 0; e < 16; ++e) acc[mt][nt][e] = 0.f;

    int srow = lane >> 3;          // 0..7 staging row within instr
    int cblk = lane & 7;           // 0..7 LDS slot (16B chunk) within row
    int scol = (cblk ^ srow) * 8;  // swizzled global chunk
    int l31 = lane & 31, kh2 = lane >> 5;
    int f7 = l31 & 7;              // read-side f(row)
    int arow[2], brow[2];
#pragma unroll
    for (int i = 0; i < 2; ++i) {
        arow[i] = wy * 64 + i * 32 + l31;
        brow[i] = wx * 64 + i * 32 + l31;
    }
    const f16* Asrc[4]; const f16* Bsrc[4]; int ldso[4];
#pragma unroll
    for (int i = 0; i < 4; ++i) {
        int row = w * 32 + i * 8 + srow;
        ldso[i] = row * 64 + cblk * 8;
        Asrc[i] = Ph + (size_t)(m0 + row) * KPATP + scol;
        Bsrc[i] = Ph + (size_t)cidx[n0 + row] * KPATP + scol;
    }
    for (int k0 = 0; k0 < KPAT; k0 += 64) {
#pragma unroll
        for (int i = 0; i < 4; ++i) {
            GLDS(Asrc[i] + k0, Ash + ldso[i]);
            GLDS(Bsrc[i] + k0, Bsh + ldso[i]);
        }
        __syncthreads();
#pragma unroll
        for (int kh = 0; kh < 4; ++kh) {
            int slot = (kh * 2 + kh2) ^ f7;
            f16x8 va[2], vb[2];
#pragma unroll
            for (int i = 0; i < 2; ++i) {
                va[i] = *(const f16x8*)&Ash[arow[i] * 64 + slot * 8];
                vb[i] = *(const f16x8*)&Bsh[brow[i] * 64 + slot * 8];
            }
#pragma unroll
            for (int mt = 0; mt < 2; ++mt)
#pragma unroll
                for (int nt = 0; nt < 2; ++nt)
                    acc[mt][nt] = __builtin_amdgcn_mfma_f32_32x32x16_f16(va[mt], vb[nt], acc[mt][nt], 0, 0, 0);
        }
        __syncthreads();
    }
    int rbase = 4 * kh2;
#pragma unroll
    for (int mt = 0; mt < 2; ++mt)
#pragma unroll
        for (int nt = 0; nt < 2; ++nt) {
            int col = n0 + wx * 64 + nt * 32 + l31;
            float rn = rnorm[cidx[col]];
#pragma unroll
            for (int rg = 0; rg < 16; ++rg) {
                int row = m0 + wy * 64 + mt * 32 + (rg & 3) + 8 * (rg >> 2) + rbase;
                S[(size_t)row * LPOS + col] = (f16)(acc[mt][nt][rg] * rn);
            }
        }
}

// ---------------------------------------------------------------------------
// FUSED softmax_mask + build_Rt (R14/R15): mutually independent per-batch
// units in one launch. bid [0,4096) -> softmax row; [4096,36864) -> build_Rt.
__global__ __launch_bounds__(256) void softmax_rt_fused(const f16* __restrict__ S,
                                                        const int* __restrict__ nk,
                                                        const float* __restrict__ mab,
                                                        f16* __restrict__ Ah,
                                                        const float* __restrict__ x1b,
                                                        const int* __restrict__ cidx,
                                                        f16* __restrict__ Rt) {
    int bid = blockIdx.x;
    int tid = threadIdx.x;
    if (bid >= 4096) {
        // ---- build_Rt ----
        int idx = (bid - 4096) * 256 + tid;     // n*4096 + j
        int j = idx & 4095, n = idx >> 12;
        if (j >= nk[1]) return;
        int p = cidx[j];
        int pu = p >> 6, pv = p & 63;
        int t = (n >> 9) & 3, s = (n >> 7) & 3, c = n & 127;
        int yy = 2 * pu - 1 + t, xx = 2 * pv - 1 + s;
        float val = 0.f;
        if (yy >= 0 && yy < 128 && xx >= 0 && xx < 128)
            val = x1b[c * 16384 + yy * 128 + xx];
        Rt[idx] = (f16)val;
        return;
    }
    // ---- softmax_mask ----
    int pos = bid;
    int nkeep = nk[0], kpad = nk[1];
    float ma = mab[pos];
    float sc = 10.0f * ma;
    const f16* Srow = S + (size_t)pos * LPOS;
    float v[16];
    float vmax = (nkeep < LPOS) ? 0.f : -3.0e38f;
#pragma unroll
    for (int i = 0; i < 2; ++i) {
        int jb = (tid + i * 256) * 8;
        if (jb < kpad) {
            f16x8 x8 = *(const f16x8*)(Srow + jb);
#pragma unroll
            for (int e = 0; e < 8; ++e) {
                float x = (jb + e < nkeep) ? (float)x8[e] * sc : -3.0e38f;
                v[i * 8 + e] = x;
                vmax = fmaxf(vmax, x);
            }
        } else {
#pragma unroll
            for (int e = 0; e < 8; ++e) v[i * 8 + e] = -3.0e38f;
        }
    }
#pragma unroll
    for (int off = 32; off; off >>= 1) vmax = fmaxf(vmax, __shfl_xor(vmax, off, 64));
    __shared__ float sred[4];
    int wid = tid >> 6;
    if ((tid & 63) == 0) sred[wid] = vmax;
    __syncthreads();
    vmax = fmaxf(fmaxf(sred[0], sred[1]), fmaxf(sred[2], sred[3]));
    __syncthreads();
    float ssum = 0.f;
#pragma unroll
    for (int i = 0; i < 16; ++i) {
        float e = (v[i] > -1.0e37f) ? __expf(v[i] - vmax) : 0.f;
        v[i] = e;
        ssum += e;
    }
#pragma unroll
    for (int off = 32; off; off >>= 1) ssum += __shfl_xor(ssum, off, 64);
    if ((tid & 63) == 0) sred[wid] = ssum;
    __syncthreads();
    float total = sred[0] + sred[1] + sred[2] + sred[3]
                + (float)(LPOS - nkeep) * __expf(-vmax);
    float inv = 1.f / total;
#pragma unroll
    for (int i = 0; i < 2; ++i) {
        int jb = (tid + i * 256) * 8;
        if (jb >= kpad) continue;
        f16x8 h;
#pragma unroll
        for (int e = 0; e < 8; ++e)
            h[e] = (jb + e < nkeep) ? (f16)(v[i * 8 + e] * inv * ma) : (f16)0.f;
        *(f16x8*)(Ah + (size_t)pos * LPOS + jb) = h;
    }
}

// ---------------------------------------------------------------------------
// 128x128 8-PHASE DECONV, 2 blocks/CU (proven R7): V = Ah . Rt^T, fp16 out.
__global__ __launch_bounds__(256, 2) void gemm_deconv128(const f16* __restrict__ A,
                                                         const f16* __restrict__ Bt,
                                                         const int* __restrict__ nk,
                                                         f16* __restrict__ V) {
    __shared__ __align__(16) f16 L[32768];     // 65536 B
    int id = blockIdx.x;
    int orig = (id & 7) * 64 + (id >> 3);      // XCD-contiguous chunks
    int mt = orig >> 4, nt = orig & 15;
    int m0 = mt * 128, n0 = nt * 128;
    int kpad = nk[1];
    int ntile = kpad >> 6;                     // even (128-padded)
    int NI = ntile >> 1;

    int tid = threadIdx.x;
    int lane = tid & 63, wid = tid >> 6;
    int wy = wid >> 1, wx = wid & 1;           // 2M x 2N wave grid
    int r16 = lane & 15, q = lane >> 4;

    int sr = tid >> 3, sc = tid & 7;
    int colo = (sc ^ (sr & 7)) * 8;            // pre-swizzled global chunk
    const f16* pA = A  + (size_t)(m0 + sr) * 4096 + colo;
    const f16* pB = Bt + (size_t)(n0 + sr) * 4096 + colo;

    int s3 = r16 & 7;
    int qs = (q ^ (s3 & 3)) * 8;
    int kf = s3 >> 2;
    const f16* aB = L + (wy * 64 + r16) * 64 + qs;
    const f16* bB = L + 8192 + (wx * 64 + r16) * 64 + qs;

    f32x4 acc[4][4];
#pragma unroll
    for (int i = 0; i < 4; ++i)
#pragma unroll
        for (int j = 0; j < 4; ++j) acc[i][j] = (f32x4){0.f, 0.f, 0.f, 0.f};

    f16x8 af[2][2], b0[2][2], bc[2][2];

#define STGA(bf, u, kt) do { \
    int kk_ = ((kt) < ntile) ? (kt) * 64 : 0; \
    GLDS(pA + (size_t)(u) * 131072 + kk_, L + (bf) * 16384 + (u) * 2048 + tid * 8); \
} while (0)
#define STGB(bf, u, kt) do { \
    int kk_ = ((kt) < ntile) ? (kt) * 64 : 0; \
    GLDS(pB + (size_t)(u) * 131072 + kk_, L + (bf) * 16384 + 8192 + (u) * 2048 + tid * 8); \
} while (0)
#define RDA(bf, msub) do { \
    _Pragma("unroll") for (int mf_ = 0; mf_ < 2; ++mf_) \
    _Pragma("unroll") for (int ks_ = 0; ks_ < 2; ++ks_) \
        af[mf_][ks_] = *(const f16x8*)(aB + (bf) * 16384 + (msub) * 2048 + mf_ * 1024 + ((ks_ ^ kf) << 5)); \
} while (0)
#define RDB(dst, bf, nsub) do { \
    _Pragma("unroll") for (int nf_ = 0; nf_ < 2; ++nf_) \
    _Pragma("unroll") for (int ks_ = 0; ks_ < 2; ++ks_) \
        dst[nf_][ks_] = *(const f16x8*)(bB + (bf) * 16384 + (nsub) * 2048 + nf_ * 1024 + ((ks_ ^ kf) << 5)); \
} while (0)
#define QMM(msub, nsub, bfr) do { \
    __builtin_amdgcn_s_setprio(1); \
    _Pragma("unroll") for (int mf_ = 0; mf_ < 2; ++mf_) \
    _Pragma("unroll") for (int nf_ = 0; nf_ < 2; ++nf_) \
    _Pragma("unroll") for (int ks_ = 0; ks_ < 2; ++ks_) \
        acc[(msub) * 2 + mf_][(nsub) * 2 + nf_] = __builtin_amdgcn_mfma_f32_16x16x32_f16( \
            af[mf_][ks_], bfr[nf_][ks_], acc[(msub) * 2 + mf_][(nsub) * 2 + nf_], 0, 0, 0); \
    __builtin_amdgcn_s_setprio(0); \
} while (0)
#define BAR()  __builtin_amdgcn_s_barrier()
#define VMW4() asm volatile("s_waitcnt vmcnt(4)" ::: "memory")

    STGB(0, 0, 0); STGB(0, 1, 0); STGB(0, 2, 0); STGB(0, 3, 0);
    STGA(0, 0, 0); STGA(0, 1, 0); STGA(0, 2, 0); STGA(0, 3, 0);
    STGB(1, 0, 1); STGB(1, 1, 1); STGB(1, 2, 1); STGB(1, 3, 1);
    VMW4(); BAR();

    for (int i = 0; i < NI; ++i) {
        int kt1 = 2 * i + 1, kt2 = 2 * i + 2, kt3 = 2 * i + 3;
        RDA(0, 0); RDB(b0, 0, 0);
        STGA(1, 0, kt1); STGA(1, 1, kt1);
        BAR(); QMM(0, 0, b0); BAR();
        RDB(bc, 0, 1);
        STGA(1, 2, kt1); STGA(1, 3, kt1);
        BAR(); QMM(0, 1, bc); BAR();
        RDA(0, 1);
        STGB(0, 0, kt2); STGB(0, 1, kt2);
        BAR(); QMM(1, 1, bc); BAR();
        STGB(0, 2, kt2); STGB(0, 3, kt2);
        BAR(); QMM(1, 0, b0);
        VMW4(); BAR();
        RDA(1, 0); RDB(b0, 1, 0);
        STGA(0, 0, kt2); STGA(0, 1, kt2);
        BAR(); QMM(0, 0, b0); BAR();
        RDB(bc, 1, 1);
        STGA(0, 2, kt2); STGA(0, 3, kt2);
        BAR(); QMM(0, 1, bc); BAR();
        RDA(1, 1);
        STGB(1, 0, kt3); STGB(1, 1, kt3);
        BAR(); QMM(1, 1, bc); BAR();
        STGB(1, 2, kt3); STGB(1, 3, kt3);
        BAR(); QMM(1, 0, b0);
        VMW4(); BAR();
    }

    asm volatile("s_waitcnt vmcnt(0)" ::: "memory");

#pragma unroll
    for (int mi = 0; mi < 4; ++mi) {
        int row = m0 + wy * 64 + mi * 16 + q * 4;
#pragma unroll
        for (int ni = 0; ni < 4; ++ni) {
            int col = n0 + wx * 64 + ni * 16 + r16;
#pragma unroll
            for (int g = 0; g < 4; ++g)
                V[(size_t)(row + g) * RPAT + col] = (f16)acc[mi][ni][g];
        }
    }
#undef STGA
#undef STGB
#undef RDA
#undef RDB
#undef QMM
#undef BAR
#undef VMW4
}

// ---------------------------------------------------------------------------
// reconstruct -> chunk-major padded layout:
// ybTp[b][yy+8][q=c>>3][xx+8][c&7] = 0.25 * sum over valid taps of V
__global__ __launch_bounds__(256) void reconstruct(const f16* __restrict__ V,
                                                   f16* __restrict__ ybTpb) {
    int idx = blockIdx.x * 256 + threadIdx.x;   // p*128 + c
    int c = idx & 127, p = idx >> 7;
    int xx = p & 127, yy = p >> 7;
    float sum = 0.f;
    int tby = (yy & 1) ? 0 : 1;
    int tbx = (xx & 1) ? 0 : 1;
#pragma unroll
    for (int dt = 0; dt < 2; ++dt) {
        int t = tby + 2 * dt;
        int u2 = yy + 1 - t;
        if (u2 < 0 || u2 >= 128) continue;
        int u = u2 >> 1;
#pragma unroll
        for (int ds = 0; ds < 2; ++ds) {
            int s = tbx + 2 * ds;
            int v2 = xx + 1 - s;
            if (v2 < 0 || v2 >= 128) continue;
            int v = v2 >> 1;
            sum += (float)V[(size_t)(u * 64 + v) * RPAT + (t * 4 + s) * 128 + c];
        }
    }
    ybTpb[(size_t)(yy + 8) * ROWS + (c >> 3) * 1152 + (xx + 8) * 8 + (c & 7)] = (f16)(0.25f * sum);
}

// ---------------------------------------------------------------------------
// Tap-decomposed implicit-GEMM grouped dilated conv via MFMA (fp16).
// Proven R5 structure: each wave computes TWO y-rows (4 independent chains).
__global__ __launch_bounds__(256, 4) void final_conv_mfma(const f16* __restrict__ ybTp,
                                                          const f16* __restrict__ Wt,
                                                          const float* __restrict__ cb,
                                                          float* __restrict__ out) {
    int id = blockIdx.x;            // 0..1023
    int p = id & 7;
    int b = p >> 1, yhalf = p & 1;
    int rest = id >> 3;             // 0..127
    int g = rest >> 5;              // 0..3
    int y = yhalf * 64 + (rest & 31) * 2;   // rows y, y+1
    int tid = threadIdx.x, w = tid >> 6, lane = tid & 63;
    int xbase = w * 32;
    int r = 1 << g;                 // RATES = 1,2,4,8
    int m = lane & 15, q = lane >> 4;
    const f16* yB0 = ybTp + (size_t)b * PPAD * 128
                   + (size_t)(y + 8) * ROWS + q * 1152 + (xbase + m + 8) * 8;
    const f16* Wg = Wt + g * 18432 + m * 128 + q * 8;

    f32x4 acc00 = (f32x4){0.f, 0.f, 0.f, 0.f};
    f32x4 acc01 = (f32x4){0.f, 0.f, 0.f, 0.f};
    f32x4 acc10 = (f32x4){0.f, 0.f, 0.f, 0.f};
    f32x4 acc11 = (f32x4){0.f, 0.f, 0.f, 0.f};

#pragma unroll
    for (int tap = 0; tap < 9; ++tap) {
        int dy = (tap / 3 - 1) * r, dx = (tap % 3 - 1) * r;
        const f16* rb0 = yB0 + (ptrdiff_t)dy * ROWS + (ptrdiff_t)dx * 8;
        const f16* rb1 = rb0 + ROWS;
        const f16* wrow = Wg + tap * 2048;
        f16x8 bf[4];
#pragma unroll
        for (int ks = 0; ks < 4; ++ks) bf[ks] = *(const f16x8*)(wrow + ks * 32);
        f16x8 a00[4], a01[4], a10[4], a11[4];
#pragma unroll
        for (int ks = 0; ks < 4; ++ks) {
            a00[ks] = *(const f16x8*)(rb0 + ks * 4608);
            a01[ks] = *(const f16x8*)(rb0 + ks * 4608 + 128);
            a10[ks] = *(const f16x8*)(rb1 + ks * 4608);
            a11[ks] = *(const f16x8*)(rb1 + ks * 4608 + 128);
        }
#pragma unroll
        for (int ks = 0; ks < 4; ++ks) {
            acc00 = __builtin_amdgcn_mfma_f32_16x16x32_f16(a00[ks], bf[ks], acc00, 0, 0, 0);
            acc01 = __builtin_amdgcn_mfma_f32_16x16x32_f16(a01[ks], bf[ks], acc01, 0, 0, 0);
            acc10 = __builtin_amdgcn_mfma_f32_16x16x32_f16(a10[ks], bf[ks], acc10, 0, 0, 0);
            acc11 = __builtin_amdgcn_mfma_f32_16x16x32_f16(a11[ks], bf[ks], acc11, 0, 0, 0);
        }
    }

    float bias = cb[g * 16 + m];
    float* orow0 = out + ((size_t)(b * 64 + g * 16 + m)) * 16384 + (size_t)y * 128;
    float* orow1 = orow0 + 128;
#pragma unroll
    for (int ri = 0; ri < 4; ++ri) {
        orow0[xbase + q * 4 + ri]      = fmaxf(acc00[ri] + bias, 0.f);
        orow0[xbase + 16 + q * 4 + ri] = fmaxf(acc01[ri] + bias, 0.f);
        orow1[xbase + q * 4 + ri]      = fmaxf(acc10[ri] + bias, 0.f);
        orow1[xbase + 16 + q * 4 + ri] = fmaxf(acc11[ri] + bias, 0.f);
    }
}

// ---------------------------------------------------------------------------
extern "C" void kernel_launch(void* const* d_in, const int* in_sizes, int n_in,
                              void* d_out, int out_size, void* d_ws, size_t ws_size,
                              hipStream_t stream) {
    const float* x1 = (const float*)d_in[0];        // (4,128,128,128)
    const float* x2 = (const float*)d_in[1];        // (4,64,64,64)
    const float* mask = (const float*)d_in[2];      // (4,1,128,128)
    const float* mask_all = (const float*)d_in[3];  // (4,1,64,64)
    const float* conv_w = (const float*)d_in[4];    // (4,16,128,3,3)
    const float* conv_b = (const float*)d_in[5];    // (4,16)
    float* out = (float*)d_out;                     // (4,64,128,128)

    char* ws = (char*)d_ws;
    f16*   Ph4   = (f16*)  (ws + 0);            // 20,971,520 B (4 x 4096 x 640)
    float* rnorm = (float*)(ws + 20971520);     //     65,536 B (4 batches)
    int*   cidx  = (int*)  (ws + 21037056);     //     69,632 B (4 batches)
    int*   nk    = (int*)  (ws + 21106688);     //         32 B (pad to 21,106,944)
    f16*   Wt    = (f16*)  (ws + 21106944);     //    147,456 B (73,728 f16 elems)
    f16*   S     = (f16*)  (ws + 21254400);     // 33,554,432 B (per-batch reuse)
    f16*   V     = (f16*)  (ws + 54808832);     // 16,777,216 B
    f16*   Ah    = (f16*)  (ws + 71586048);     // 33,554,432 B
    f16*   Rt    = (f16*)  (ws + 105140480);    // 16,777,216 B
    f16*   ybTp  = (f16*)  (ws + 121917696);    // 21,233,664 B (ends 143,151,360)

    prologue_fused<<<9572, 256, 0, stream>>>(x2, Ph4, rnorm, mask, cidx, nk,
                                             ybTp, conv_w, Wt);
    for (int b = 0; b < 4; ++b) {
        const float* x1b = x1 + (size_t)b * 128 * 16384;
        const int* cb_idx = cidx + b * 4352;
        const int* nkb = nk + b * 2;
        const f16* Phb = Ph4 + (size_t)b * 4096 * KPATP;
        gemm_score64<<<dim3(32, 32), 256, 0, stream>>>(Phb, cb_idx, rnorm + b * 4096, nkb, S);
        softmax_rt_fused<<<36864, 256, 0, stream>>>(S, nkb, mask_all + (size_t)b * 4096,
                                                    Ah, x1b, cb_idx, Rt);
        gemm_deconv128<<<512, 256, 0, stream>>>(Ah, Rt, nkb, V);
        reconstruct<<<8192, 256, 0, stream>>>(V, ybTp + (size_t)b * PPAD * 128);
    }
    final_conv_mfma<<<1024, 256, 0, stream>>>(ybTp, Wt, conv_b, out);
}

// Round 17
// 565.785 us; speedup vs baseline: 1.0660x; 1.0131x over previous
//
#include <hip/hip_runtime.h>
#include <math.h>

typedef _Float16 f16;
typedef __attribute__((ext_vector_type(8))) _Float16 f16x8;
typedef __attribute__((ext_vector_type(4))) float f32x4;
typedef __attribute__((ext_vector_type(16))) float f32x16;

#define LPOS 4096      // 64*64 positions / patches
#define KPAT 576       // 64ch * 3*3 patch (= exactly 9 BK=64 tiles)
#define KPATP 640      // Ph row stride (256B-aligned rows; cols 576..639 zeroed)
#define RPAT 2048      // 128ch * 4*4 raw patch
#define PPAD 20736     // 144*144 padded positions for ybT
#define ROWS 18432     // elems per padded row: 16 chunks * 144 x * 8

#define GLDS(g, l) __builtin_amdgcn_global_load_lds( \
    (const __attribute__((address_space(1))) void*)(g), \
    (__attribute__((address_space(3))) void*)(l), 16, 0, 0)

// ---------------------------------------------------------------------------
// FUSED PROLOGUE: 4 independent prologue kernels in one launch, branched on
// blockIdx ranges. R16: build_P_norm branch restructured for MLP — explicit
// val[9] + unrolled load loop puts 9 independent gathers in flight per wave
// (R15 measured VGPR=16 -> compiler had serialized the 9 load-store pairs).
//   bid [0,4096)      : build_P_norm (4 waves x 1 pos each; 16384 pos total)
//   bid [4096,4100)   : compact_mask_all (b = bid-4096)
//   bid [4100,9284)   : zero_halo
//   bid [9284,9572)   : prep_w
__global__ __launch_bounds__(256) void prologue_fused(const float* __restrict__ x2,
                                                      f16* __restrict__ Ph4,
                                                      float* __restrict__ rnorm4,
                                                      const float* __restrict__ mask,
                                                      int* __restrict__ cidx_all,
                                                      int* __restrict__ nk_all,
                                                      f16* __restrict__ ybTp,
                                                      const float* __restrict__ cw,
                                                      f16* __restrict__ Wt) {
    int bid = blockIdx.x;
    int tid = threadIdx.x;
    if (bid < 4096) {
        // ---- build_P_norm: global pos = bid*4 + wave ----
        int lane = tid & 63;
        int gp = bid * 4 + (tid >> 6);          // 0..16383
        int b = gp >> 12, pos = gp & 4095;
        const float* x2b = x2 + (size_t)b * 64 * 4096;
        f16* Ph = Ph4 + (size_t)b * 4096 * KPATP;
        float* rnorm = rnorm4 + b * 4096;
        int u = pos >> 6, v = pos & 63;
        float val[9];
#pragma unroll
        for (int i = 0; i < 9; ++i) {           // 9 independent gathers in flight
            int k = lane + i * 64;
            int c = k / 9, r9 = k % 9;
            int di = r9 / 3, dj = r9 % 3;
            int yy = u + di - 1, xx = v + dj - 1;
            val[i] = 0.f;
            if (yy >= 0 && yy < 64 && xx >= 0 && xx < 64)
                val[i] = x2b[c * 4096 + yy * 64 + xx];
        }
        float ss = 0.f;
#pragma unroll
        for (int i = 0; i < 9; ++i) {
            Ph[pos * KPATP + lane + i * 64] = (f16)val[i];
            ss += val[i] * val[i];
        }
        Ph[pos * KPATP + KPAT + lane] = (f16)0.f;   // zero 64-wide K-pad tail
#pragma unroll
        for (int off = 32; off; off >>= 1) ss += __shfl_xor(ss, off, 64);
        if (lane == 0) rnorm[pos] = 1.f / fmaxf(sqrtf(ss), 1e-4f);
        return;
    }
    if (bid < 4100) {
        // ---- compact_mask_all ----
        int b = bid - 4096;
        const float* maskb = mask + (size_t)b * 16384;
        int* cidx = cidx_all + b * 4352;
        int* nk = nk_all + b * 2;
        int keep[16];
        int cnt = 0;
#pragma unroll
        for (int e = 0; e < 16; ++e) {
            int pos = tid * 16 + e;
            int pu = pos >> 6, pv = pos & 63;
            float s = 0.f;
            for (int t = 0; t < 4; ++t)
                for (int w = 0; w < 4; ++w) {
                    int yy = 2 * pu - 1 + t, xx = 2 * pv - 1 + w;
                    if (yy >= 0 && yy < 128 && xx >= 0 && xx < 128)
                        s += maskb[yy * 128 + xx];
                }
            keep[e] = (s == 0.f) ? 1 : 0;
            cnt += keep[e];
        }
        __shared__ int ps[256];
        ps[tid] = cnt;
        __syncthreads();
        for (int off = 1; off < 256; off <<= 1) {
            int v = (tid >= off) ? ps[tid - off] : 0;
            __syncthreads();
            ps[tid] += v;
            __syncthreads();
        }
        int total = ps[255];
        int base = ps[tid] - cnt;   // exclusive prefix
#pragma unroll
        for (int e = 0; e < 16; ++e)
            if (keep[e]) cidx[base++] = tid * 16 + e;
        for (int i = total + tid; i < 4352; i += 256) cidx[i] = 0;
        if (tid == 0) { nk[0] = total; nk[1] = (total + 127) & ~127; }
        return;
    }
    if (bid < 9284) {
        // ---- zero_halo ----
        int idx = (bid - 4100) * 256 + tid;
        int b = idx / 331776; if (b >= 4) return;
        int rem = idx % 331776;                 // 144*144*16
        int q = rem & 15, pos = rem >> 4;
        int yy = pos / 144, xx = pos % 144;
        if (yy >= 8 && yy < 136 && xx >= 8 && xx < 136) return;
        *(f16x8*)(ybTp + (size_t)b * PPAD * 128 + (size_t)yy * ROWS + q * 1152 + xx * 8) = (f16x8){};
        return;
    }
    {
        // ---- prep_w  (73,728 ELEMENTS = 147,456 BYTES in workspace!) ----
        int idx = (bid - 9284) * 256 + tid;
        if (idx >= 4 * 9 * 16 * 128) return;
        int g = idx / 18432, rem = idx % 18432;
        int tap = rem >> 11, oc = (rem >> 7) & 15, c = rem & 127;
        Wt[idx] = (f16)cw[(((g * 16 + oc) * 128 + c) * 9) + tap];
    }
}

// ---------------------------------------------------------------------------
// SCORE GEMM on the R2-proven fallback skeleton (deterministic: single-buffer
// LDS, BK=64, 2 __syncthreads per K-step, NO hand vmcnt). K loop runs the
// 9 real tiles only (576 = 9*64).
__global__ __launch_bounds__(256) void gemm_score64(const f16* __restrict__ Ph,
                                                    const int* __restrict__ cidx,
                                                    const float* __restrict__ rnorm,
                                                    const int* __restrict__ nk,
                                                    f16* __restrict__ S) {
    __shared__ f16 Ash[128 * 64], Bsh[128 * 64];
    int n0 = blockIdx.x * 128;
    if (n0 >= nk[0]) return;    // fully-masked column tile (block-uniform)
    int m0 = blockIdx.y * 128;

    int tid = threadIdx.x;
    int w = tid >> 6, lane = tid & 63;
    int wy = w >> 1, wx = w & 1;
    f32x16 acc[2][2];
#pragma unroll
    for (int mt = 0; mt < 2; ++mt)
#pragma unroll
        for (int nt = 0; nt < 2; ++nt)
#pragma unroll
            for (int e = 0; e < 16; ++e) acc[mt][nt][e] = 0.f;

    int srow = lane >> 3;          // 0..7 staging row within instr
    int cblk = lane & 7;           // 0..7 LDS slot (16B chunk) within row
    int scol = (cblk ^ srow) * 8;  // swizzled global chunk
    int l31 = lane & 31, kh2 = lane >> 5;
    int f7 = l31 & 7;              // read-side f(row)
    int arow[2], brow[2];
#pragma unroll
    for (int i = 0; i < 2; ++i) {
        arow[i] = wy * 64 + i * 32 + l31;
        brow[i] = wx * 64 + i * 32 + l31;
    }
    const f16* Asrc[4]; const f16* Bsrc[4]; int ldso[4];
#pragma unroll
    for (int i = 0; i < 4; ++i) {
        int row = w * 32 + i * 8 + srow;
        ldso[i] = row * 64 + cblk * 8;
        Asrc[i] = Ph + (size_t)(m0 + row) * KPATP + scol;
        Bsrc[i] = Ph + (size_t)cidx[n0 + row] * KPATP + scol;
    }
    for (int k0 = 0; k0 < KPAT; k0 += 64) {
#pragma unroll
        for (int i = 0; i < 4; ++i) {
            GLDS(Asrc[i] + k0, Ash + ldso[i]);
            GLDS(Bsrc[i] + k0, Bsh + ldso[i]);
        }
        __syncthreads();
#pragma unroll
        for (int kh = 0; kh < 4; ++kh) {
            int slot = (kh * 2 + kh2) ^ f7;
            f16x8 va[2], vb[2];
#pragma unroll
            for (int i = 0; i < 2; ++i) {
                va[i] = *(const f16x8*)&Ash[arow[i] * 64 + slot * 8];
                vb[i] = *(const f16x8*)&Bsh[brow[i] * 64 + slot * 8];
            }
#pragma unroll
            for (int mt = 0; mt < 2; ++mt)
#pragma unroll
                for (int nt = 0; nt < 2; ++nt)
                    acc[mt][nt] = __builtin_amdgcn_mfma_f32_32x32x16_f16(va[mt], vb[nt], acc[mt][nt], 0, 0, 0);
        }
        __syncthreads();
    }
    int rbase = 4 * kh2;
#pragma unroll
    for (int mt = 0; mt < 2; ++mt)
#pragma unroll
        for (int nt = 0; nt < 2; ++nt) {
            int col = n0 + wx * 64 + nt * 32 + l31;
            float rn = rnorm[cidx[col]];
#pragma unroll
            for (int rg = 0; rg < 16; ++rg) {
                int row = m0 + wy * 64 + mt * 32 + (rg & 3) + 8 * (rg >> 2) + rbase;
                S[(size_t)row * LPOS + col] = (f16)(acc[mt][nt][rg] * rn);
            }
        }
}

// ---------------------------------------------------------------------------
// FUSED softmax_mask + build_Rt: mutually independent per-batch units in one
// launch. bid [0,4096) -> softmax row; [4096,36864) -> build_Rt.
__global__ __launch_bounds__(256) void softmax_rt_fused(const f16* __restrict__ S,
                                                        const int* __restrict__ nk,
                                                        const float* __restrict__ mab,
                                                        f16* __restrict__ Ah,
                                                        const float* __restrict__ x1b,
                                                        const int* __restrict__ cidx,
                                                        f16* __restrict__ Rt) {
    int bid = blockIdx.x;
    int tid = threadIdx.x;
    if (bid >= 4096) {
        // ---- build_Rt ----
        int idx = (bid - 4096) * 256 + tid;     // n*4096 + j
        int j = idx & 4095, n = idx >> 12;
        if (j >= nk[1]) return;
        int p = cidx[j];
        int pu = p >> 6, pv = p & 63;
        int t = (n >> 9) & 3, s = (n >> 7) & 3, c = n & 127;
        int yy = 2 * pu - 1 + t, xx = 2 * pv - 1 + s;
        float val = 0.f;
        if (yy >= 0 && yy < 128 && xx >= 0 && xx < 128)
            val = x1b[c * 16384 + yy * 128 + xx];
        Rt[idx] = (f16)val;
        return;
    }
    // ---- softmax_mask ----
    int pos = bid;
    int nkeep = nk[0], kpad = nk[1];
    float ma = mab[pos];
    float sc = 10.0f * ma;
    const f16* Srow = S + (size_t)pos * LPOS;
    float v[16];
    float vmax = (nkeep < LPOS) ? 0.f : -3.0e38f;
#pragma unroll
    for (int i = 0; i < 2; ++i) {
        int jb = (tid + i * 256) * 8;
        if (jb < kpad) {
            f16x8 x8 = *(const f16x8*)(Srow + jb);
#pragma unroll
            for (int e = 0; e < 8; ++e) {
                float x = (jb + e < nkeep) ? (float)x8[e] * sc : -3.0e38f;
                v[i * 8 + e] = x;
                vmax = fmaxf(vmax, x);
            }
        } else {
#pragma unroll
            for (int e = 0; e < 8; ++e) v[i * 8 + e] = -3.0e38f;
        }
    }
#pragma unroll
    for (int off = 32; off; off >>= 1) vmax = fmaxf(vmax, __shfl_xor(vmax, off, 64));
    __shared__ float sred[4];
    int wid = tid >> 6;
    if ((tid & 63) == 0) sred[wid] = vmax;
    __syncthreads();
    vmax = fmaxf(fmaxf(sred[0], sred[1]), fmaxf(sred[2], sred[3]));
    __syncthreads();
    float ssum = 0.f;
#pragma unroll
    for (int i = 0; i < 16; ++i) {
        float e = (v[i] > -1.0e37f) ? __expf(v[i] - vmax) : 0.f;
        v[i] = e;
        ssum += e;
    }
#pragma unroll
    for (int off = 32; off; off >>= 1) ssum += __shfl_xor(ssum, off, 64);
    if ((tid & 63) == 0) sred[wid] = ssum;
    __syncthreads();
    float total = sred[0] + sred[1] + sred[2] + sred[3]
                + (float)(LPOS - nkeep) * __expf(-vmax);
    float inv = 1.f / total;
#pragma unroll
    for (int i = 0; i < 2; ++i) {
        int jb = (tid + i * 256) * 8;
        if (jb >= kpad) continue;
        f16x8 h;
#pragma unroll
        for (int e = 0; e < 8; ++e)
            h[e] = (jb + e < nkeep) ? (f16)(v[i * 8 + e] * inv * ma) : (f16)0.f;
        *(f16x8*)(Ah + (size_t)pos * LPOS + jb) = h;
    }
}

// ---------------------------------------------------------------------------
// 128x128 8-PHASE DECONV, 2 blocks/CU (proven R7): V = Ah . Rt^T, fp16 out.
__global__ __launch_bounds__(256, 2) void gemm_deconv128(const f16* __restrict__ A,
                                                         const f16* __restrict__ Bt,
                                                         const int* __restrict__ nk,
                                                         f16* __restrict__ V) {
    __shared__ __align__(16) f16 L[32768];     // 65536 B
    int id = blockIdx.x;
    int orig = (id & 7) * 64 + (id >> 3);      // XCD-contiguous chunks
    int mt = orig >> 4, nt = orig & 15;
    int m0 = mt * 128, n0 = nt * 128;
    int kpad = nk[1];
    int ntile = kpad >> 6;                     // even (128-padded)
    int NI = ntile >> 1;

    int tid = threadIdx.x;
    int lane = tid & 63, wid = tid >> 6;
    int wy = wid >> 1, wx = wid & 1;           // 2M x 2N wave grid
    int r16 = lane & 15, q = lane >> 4;

    int sr = tid >> 3, sc = tid & 7;
    int colo = (sc ^ (sr & 7)) * 8;            // pre-swizzled global chunk
    const f16* pA = A  + (size_t)(m0 + sr) * 4096 + colo;
    const f16* pB = Bt + (size_t)(n0 + sr) * 4096 + colo;

    int s3 = r16 & 7;
    int qs = (q ^ (s3 & 3)) * 8;
    int kf = s3 >> 2;
    const f16* aB = L + (wy * 64 + r16) * 64 + qs;
    const f16* bB = L + 8192 + (wx * 64 + r16) * 64 + qs;

    f32x4 acc[4][4];
#pragma unroll
    for (int i = 0; i < 4; ++i)
#pragma unroll
        for (int j = 0; j < 4; ++j) acc[i][j] = (f32x4){0.f, 0.f, 0.f, 0.f};

    f16x8 af[2][2], b0[2][2], bc[2][2];

#define STGA(bf, u, kt) do { \
    int kk_ = ((kt) < ntile) ? (kt) * 64 : 0; \
    GLDS(pA + (size_t)(u) * 131072 + kk_, L + (bf) * 16384 + (u) * 2048 + tid * 8); \
} while (0)
#define STGB(bf, u, kt) do { \
    int kk_ = ((kt) < ntile) ? (kt) * 64 : 0; \
    GLDS(pB + (size_t)(u) * 131072 + kk_, L + (bf) * 16384 + 8192 + (u) * 2048 + tid * 8); \
} while (0)
#define RDA(bf, msub) do { \
    _Pragma("unroll") for (int mf_ = 0; mf_ < 2; ++mf_) \
    _Pragma("unroll") for (int ks_ = 0; ks_ < 2; ++ks_) \
        af[mf_][ks_] = *(const f16x8*)(aB + (bf) * 16384 + (msub) * 2048 + mf_ * 1024 + ((ks_ ^ kf) << 5)); \
} while (0)
#define RDB(dst, bf, nsub) do { \
    _Pragma("unroll") for (int nf_ = 0; nf_ < 2; ++nf_) \
    _Pragma("unroll") for (int ks_ = 0; ks_ < 2; ++ks_) \
        dst[nf_][ks_] = *(const f16x8*)(bB + (bf) * 16384 + (nsub) * 2048 + nf_ * 1024 + ((ks_ ^ kf) << 5)); \
} while (0)
#define QMM(msub, nsub, bfr) do { \
    __builtin_amdgcn_s_setprio(1); \
    _Pragma("unroll") for (int mf_ = 0; mf_ < 2; ++mf_) \
    _Pragma("unroll") for (int nf_ = 0; nf_ < 2; ++nf_) \
    _Pragma("unroll") for (int ks_ = 0; ks_ < 2; ++ks_) \
        acc[(msub) * 2 + mf_][(nsub) * 2 + nf_] = __builtin_amdgcn_mfma_f32_16x16x32_f16( \
            af[mf_][ks_], bfr[nf_][ks_], acc[(msub) * 2 + mf_][(nsub) * 2 + nf_], 0, 0, 0); \
    __builtin_amdgcn_s_setprio(0); \
} while (0)
#define BAR()  __builtin_amdgcn_s_barrier()
#define VMW4() asm volatile("s_waitcnt vmcnt(4)" ::: "memory")

    STGB(0, 0, 0); STGB(0, 1, 0); STGB(0, 2, 0); STGB(0, 3, 0);
    STGA(0, 0, 0); STGA(0, 1, 0); STGA(0, 2, 0); STGA(0, 3, 0);
    STGB(1, 0, 1); STGB(1, 1, 1); STGB(1, 2, 1); STGB(1, 3, 1);
    VMW4(); BAR();

    for (int i = 0; i < NI; ++i) {
        int kt1 = 2 * i + 1, kt2 = 2 * i + 2, kt3 = 2 * i + 3;
        RDA(0, 0); RDB(b0, 0, 0);
        STGA(1, 0, kt1); STGA(1, 1, kt1);
        BAR(); QMM(0, 0, b0); BAR();
        RDB(bc, 0, 1);
        STGA(1, 2, kt1); STGA(1, 3, kt1);
        BAR(); QMM(0, 1, bc); BAR();
        RDA(0, 1);
        STGB(0, 0, kt2); STGB(0, 1, kt2);
        BAR(); QMM(1, 1, bc); BAR();
        STGB(0, 2, kt2); STGB(0, 3, kt2);
        BAR(); QMM(1, 0, b0);
        VMW4(); BAR();
        RDA(1, 0); RDB(b0, 1, 0);
        STGA(0, 0, kt2); STGA(0, 1, kt2);
        BAR(); QMM(0, 0, b0); BAR();
        RDB(bc, 1, 1);
        STGA(0, 2, kt2); STGA(0, 3, kt2);
        BAR(); QMM(0, 1, bc); BAR();
        RDA(1, 1);
        STGB(1, 0, kt3); STGB(1, 1, kt3);
        BAR(); QMM(1, 1, bc); BAR();
        STGB(1, 2, kt3); STGB(1, 3, kt3);
        BAR(); QMM(1, 0, b0);
        VMW4(); BAR();
    }

    asm volatile("s_waitcnt vmcnt(0)" ::: "memory");

#pragma unroll
    for (int mi = 0; mi < 4; ++mi) {
        int row = m0 + wy * 64 + mi * 16 + q * 4;
#pragma unroll
        for (int ni = 0; ni < 4; ++ni) {
            int col = n0 + wx * 64 + ni * 16 + r16;
#pragma unroll
            for (int g = 0; g < 4; ++g)
                V[(size_t)(row + g) * RPAT + col] = (f16)acc[mi][ni][g];
        }
    }
#undef STGA
#undef STGB
#undef RDA
#undef RDB
#undef QMM
#undef BAR
#undef VMW4
}

// ---------------------------------------------------------------------------
// reconstruct -> chunk-major padded layout:
// ybTp[b][yy+8][q=c>>3][xx+8][c&7] = 0.25 * sum over valid taps of V
__global__ __launch_bounds__(256) void reconstruct(const f16* __restrict__ V,
                                                   f16* __restrict__ ybTpb) {
    int idx = blockIdx.x * 256 + threadIdx.x;   // p*128 + c
    int c = idx & 127, p = idx >> 7;
    int xx = p & 127, yy = p >> 7;
    float sum = 0.f;
    int tby = (yy & 1) ? 0 : 1;
    int tbx = (xx & 1) ? 0 : 1;
#pragma unroll
    for (int dt = 0; dt < 2; ++dt) {
        int t = tby + 2 * dt;
        int u2 = yy + 1 - t;
        if (u2 < 0 || u2 >= 128) continue;
        int u = u2 >> 1;
#pragma unroll
        for (int ds = 0; ds < 2; ++ds) {
            int s = tbx + 2 * ds;
            int v2 = xx + 1 - s;
            if (v2 < 0 || v2 >= 128) continue;
            int v = v2 >> 1;
            sum += (float)V[(size_t)(u * 64 + v) * RPAT + (t * 4 + s) * 128 + c];
        }
    }
    ybTpb[(size_t)(yy + 8) * ROWS + (c >> 3) * 1152 + (xx + 8) * 8 + (c & 7)] = (f16)(0.25f * sum);
}

// ---------------------------------------------------------------------------
// Tap-decomposed implicit-GEMM grouped dilated conv via MFMA (fp16).
// Proven R5 structure: each wave computes TWO y-rows (4 independent chains).
__global__ __launch_bounds__(256, 4) void final_conv_mfma(const f16* __restrict__ ybTp,
                                                          const f16* __restrict__ Wt,
                                                          const float* __restrict__ cb,
                                                          float* __restrict__ out) {
    int id = blockIdx.x;            // 0..1023
    int p = id & 7;
    int b = p >> 1, yhalf = p & 1;
    int rest = id >> 3;             // 0..127
    int g = rest >> 5;              // 0..3
    int y = yhalf * 64 + (rest & 31) * 2;   // rows y, y+1
    int tid = threadIdx.x, w = tid >> 6, lane = tid & 63;
    int xbase = w * 32;
    int r = 1 << g;                 // RATES = 1,2,4,8
    int m = lane & 15, q = lane >> 4;
    const f16* yB0 = ybTp + (size_t)b * PPAD * 128
                   + (size_t)(y + 8) * ROWS + q * 1152 + (xbase + m + 8) * 8;
    const f16* Wg = Wt + g * 18432 + m * 128 + q * 8;

    f32x4 acc00 = (f32x4){0.f, 0.f, 0.f, 0.f};
    f32x4 acc01 = (f32x4){0.f, 0.f, 0.f, 0.f};
    f32x4 acc10 = (f32x4){0.f, 0.f, 0.f, 0.f};
    f32x4 acc11 = (f32x4){0.f, 0.f, 0.f, 0.f};

#pragma unroll
    for (int tap = 0; tap < 9; ++tap) {
        int dy = (tap / 3 - 1) * r, dx = (tap % 3 - 1) * r;
        const f16* rb0 = yB0 + (ptrdiff_t)dy * ROWS + (ptrdiff_t)dx * 8;
        const f16* rb1 = rb0 + ROWS;
        const f16* wrow = Wg + tap * 2048;
        f16x8 bf[4];
#pragma unroll
        for (int ks = 0; ks < 4; ++ks) bf[ks] = *(const f16x8*)(wrow + ks * 32);
        f16x8 a00[4], a01[4], a10[4], a11[4];
#pragma unroll
        for (int ks = 0; ks < 4; ++ks) {
            a00[ks] = *(const f16x8*)(rb0 + ks * 4608);
            a01[ks] = *(const f16x8*)(rb0 + ks * 4608 + 128);
            a10[ks] = *(const f16x8*)(rb1 + ks * 4608);
            a11[ks] = *(const f16x8*)(rb1 + ks * 4608 + 128);
        }
#pragma unroll
        for (int ks = 0; ks < 4; ++ks) {
            acc00 = __builtin_amdgcn_mfma_f32_16x16x32_f16(a00[ks], bf[ks], acc00, 0, 0, 0);
            acc01 = __builtin_amdgcn_mfma_f32_16x16x32_f16(a01[ks], bf[ks], acc01, 0, 0, 0);
            acc10 = __builtin_amdgcn_mfma_f32_16x16x32_f16(a10[ks], bf[ks], acc10, 0, 0, 0);
            acc11 = __builtin_amdgcn_mfma_f32_16x16x32_f16(a11[ks], bf[ks], acc11, 0, 0, 0);
        }
    }

    float bias = cb[g * 16 + m];
    float* orow0 = out + ((size_t)(b * 64 + g * 16 + m)) * 16384 + (size_t)y * 128;
    float* orow1 = orow0 + 128;
#pragma unroll
    for (int ri = 0; ri < 4; ++ri) {
        orow0[xbase + q * 4 + ri]      = fmaxf(acc00[ri] + bias, 0.f);
        orow0[xbase + 16 + q * 4 + ri] = fmaxf(acc01[ri] + bias, 0.f);
        orow1[xbase + q * 4 + ri]      = fmaxf(acc10[ri] + bias, 0.f);
        orow1[xbase + 16 + q * 4 + ri] = fmaxf(acc11[ri] + bias, 0.f);
    }
}

// ---------------------------------------------------------------------------
extern "C" void kernel_launch(void* const* d_in, const int* in_sizes, int n_in,
                              void* d_out, int out_size, void* d_ws, size_t ws_size,
                              hipStream_t stream) {
    const float* x1 = (const float*)d_in[0];        // (4,128,128,128)
    const float* x2 = (const float*)d_in[1];        // (4,64,64,64)
    const float* mask = (const float*)d_in[2];      // (4,1,128,128)
    const float* mask_all = (const float*)d_in[3];  // (4,1,64,64)
    const float* conv_w = (const float*)d_in[4];    // (4,16,128,3,3)
    const float* conv_b = (const float*)d_in[5];    // (4,16)
    float* out = (float*)d_out;                     // (4,64,128,128)

    char* ws = (char*)d_ws;
    f16*   Ph4   = (f16*)  (ws + 0);            // 20,971,520 B (4 x 4096 x 640)
    float* rnorm = (float*)(ws + 20971520);     //     65,536 B (4 batches)
    int*   cidx  = (int*)  (ws + 21037056);     //     69,632 B (4 batches)
    int*   nk    = (int*)  (ws + 21106688);     //         32 B (pad to 21,106,944)
    f16*   Wt    = (f16*)  (ws + 21106944);     //    147,456 B (73,728 f16 elems)
    f16*   S     = (f16*)  (ws + 21254400);     // 33,554,432 B (per-batch reuse)
    f16*   V     = (f16*)  (ws + 54808832);     // 16,777,216 B
    f16*   Ah    = (f16*)  (ws + 71586048);     // 33,554,432 B
    f16*   Rt    = (f16*)  (ws + 105140480);    // 16,777,216 B
    f16*   ybTp  = (f16*)  (ws + 121917696);    // 21,233,664 B (ends 143,151,360)

    prologue_fused<<<9572, 256, 0, stream>>>(x2, Ph4, rnorm, mask, cidx, nk,
                                             ybTp, conv_w, Wt);
    for (int b = 0; b < 4; ++b) {
        const float* x1b = x1 + (size_t)b * 128 * 16384;
        const int* cb_idx = cidx + b * 4352;
        const int* nkb = nk + b * 2;
        const f16* Phb = Ph4 + (size_t)b * 4096 * KPATP;
        gemm_score64<<<dim3(32, 32), 256, 0, stream>>>(Phb, cb_idx, rnorm + b * 4096, nkb, S);
        softmax_rt_fused<<<36864, 256, 0, stream>>>(S, nkb, mask_all + (size_t)b * 4096,
                                                    Ah, x1b, cb_idx, Rt);
        gemm_deconv128<<<512, 256, 0, stream>>>(Ah, Rt, nkb, V);
        reconstruct<<<8192, 256, 0, stream>>>(V, ybTp + (size_t)b * PPAD * 128);
    }
    final_conv_mfma<<<1024, 256, 0, stream>>>(ybTp, Wt, conv_b, out);
}